// Round 2
// baseline (8618.323 us; speedup 1.0000x reference)
//
#include <hip/hip_runtime.h>
#include <cstddef>
#include <cstdint>

#define DIM 2560
#define NH 40
#define HDD 64
#define SD 64
#define KC 4
#define BB 2
#define LL 2048
#define MTOT (BB*LL)      // 4096
#define NPROJ (NH*3*SD)   // 7680

typedef unsigned short u16;

__device__ inline float bf2f(u16 u) { return __uint_as_float(((unsigned)u) << 16); }
__device__ inline u16 f2bf(float f) {
  unsigned x = __float_as_uint(f);
  unsigned r = (x + 0x7fffu + ((x >> 16) & 1u)) >> 16;   // RNE
  return (u16)r;
}

// ---------------------------------------------------------------
// Block reduce (sum, sumsq) over 256 threads, result to all lanes
// ---------------------------------------------------------------
__device__ inline void block_reduce2(float& sum, float& sq, float* red) {
  #pragma unroll
  for (int off = 32; off; off >>= 1) {
    sum += __shfl_down(sum, off, 64);
    sq  += __shfl_down(sq,  off, 64);
  }
  int wid = threadIdx.x >> 6, lane = threadIdx.x & 63;
  if (lane == 0) { red[wid*2] = sum; red[wid*2+1] = sq; }
  __syncthreads();
  sum = red[0] + red[2] + red[4] + red[6];
  sq  = red[1] + red[3] + red[5] + red[7];
}

// ---------------------------------------------------------------
// diagnostic fill (used when ws_size is insufficient)
// ---------------------------------------------------------------
__global__ __launch_bounds__(256) void fill_kernel(float* p, int n, float v) {
  int i = blockIdx.x * 256 + threadIdx.x;
  if (i < n) p[i] = v;
}

// ---------------------------------------------------------------
// conv (causal depthwise, K=4) + residual + LayerNorm1 -> bf16
// ---------------------------------------------------------------
__global__ __launch_bounds__(256) void conv_ln1_kernel(
    const float* __restrict__ x, const float* __restrict__ cw,
    const float* __restrict__ g1, const float* __restrict__ b1,
    u16* __restrict__ x1) {
  __shared__ float red[8];
  int bl = blockIdx.x;
  int l  = bl & (LL - 1);
  int t  = threadIdx.x;
  const float* xr = x + (size_t)bl * DIM;
  float vals[10];
  float sum = 0.f, sq = 0.f;
  #pragma unroll
  for (int i = 0; i < 10; ++i) {
    int d = t + 256 * i;
    float acc = xr[d];
    #pragma unroll
    for (int j = 0; j < KC; ++j) {
      int ll = l - (KC - 1) + j;
      if (ll >= 0) acc += x[(size_t)(bl - l + ll) * DIM + d] * cw[d * KC + j];
    }
    vals[i] = acc; sum += acc; sq += acc * acc;
  }
  block_reduce2(sum, sq, red);
  float mean = sum * (1.f / DIM);
  float var  = sq * (1.f / DIM) - mean * mean;
  float rstd = rsqrtf(var + 1e-5f);
  u16* orow = x1 + (size_t)bl * DIM;
  #pragma unroll
  for (int i = 0; i < 10; ++i) {
    int d = t + 256 * i;
    orow[d] = f2bf((vals[i] - mean) * rstd * g1[d] + b1[d]);
  }
}

// ---------------------------------------------------------------
// LN2: out = LN(x1 + y2), bf16 inputs -> fp32 out
// ---------------------------------------------------------------
__global__ __launch_bounds__(256) void ln2_kernel(
    const u16* __restrict__ x1, const u16* __restrict__ y2,
    const float* __restrict__ g2, const float* __restrict__ b2,
    float* __restrict__ out) {
  __shared__ float red[8];
  int bl = blockIdx.x;
  int t  = threadIdx.x;
  const u16* ar = x1 + (size_t)bl * DIM;
  const u16* br = y2 + (size_t)bl * DIM;
  float vals[10];
  float sum = 0.f, sq = 0.f;
  #pragma unroll
  for (int i = 0; i < 10; ++i) {
    int d = t + 256 * i;
    float v = bf2f(ar[d]) + bf2f(br[d]);
    vals[i] = v; sum += v; sq += v * v;
  }
  block_reduce2(sum, sq, red);
  float mean = sum * (1.f / DIM);
  float var  = sq * (1.f / DIM) - mean * mean;
  float rstd = rsqrtf(var + 1e-5f);
  float* orow = out + (size_t)bl * DIM;
  #pragma unroll
  for (int i = 0; i < 10; ++i) {
    int d = t + 256 * i;
    orow[d] = (vals[i] - mean) * rstd * g2[d] + b2[d];
  }
}

// ---------------------------------------------------------------
// Tiled GEMM:  C = epi(A[M,K](bf16) @ W[N,K]^T(fp32) + bias)
// BM=BN=64, BK=16, 256 threads, 4x4 micro-tile. bf16 output.
// MODE: 0 plain        -> C1 = acc1
//       2 decay        -> C1 = sigmoid(-(acc1+bias))   (= exp(-softplus))
//       3 dual r/g     -> C1 = sigmoid(acc1), C2 = sigmoid(acc2)
//       4 dual kv      -> C1 = acc1 * acc2
// GATHER: A is proj with dt col remap (row stride NPROJ, col h*192+s)
// ---------------------------------------------------------------
template<int MODE, bool GATHER>
__global__ __launch_bounds__(256) void gemm_bt(
    const u16* __restrict__ A, const float* __restrict__ W1,
    const float* __restrict__ W2, const float* __restrict__ bias,
    u16* __restrict__ C1, u16* __restrict__ C2,
    int N, int K) {
  constexpr bool DUAL = (MODE == 3 || MODE == 4);
  __shared__ float As[16][64];
  __shared__ float W1s[16][64];
  __shared__ float W2s[DUAL ? 16 : 1][64];
  int t  = threadIdx.x;
  int m0 = blockIdx.y * 64;
  int n0 = blockIdx.x * 64;
  int tx = t & 15, ty = t >> 4;
  int lr = t >> 2;            // tile row/col 0..63 for loading
  int lk = (t & 3) * 4;       // k offset {0,4,8,12}
  float acc1[4][4] = {};
  float acc2[4][4] = {};

  for (int k0 = 0; k0 < K; k0 += 16) {
    // ---- A tile (bf16 -> fp32 LDS)
    {
      int row = m0 + lr;
      ushort4 av;
      if (!GATHER) {
        av = *(const ushort4*)(A + (size_t)row * K + k0 + lk);
      } else {
        int kk = k0 + lk;
        int h = kk >> 6, s = kk & 63;
        av = *(const ushort4*)(A + (size_t)row * NPROJ + h * 192 + s);
      }
      As[lk+0][lr] = bf2f(av.x); As[lk+1][lr] = bf2f(av.y);
      As[lk+2][lr] = bf2f(av.z); As[lk+3][lr] = bf2f(av.w);
    }
    // ---- W tiles (fp32)
    {
      int col = n0 + lr;
      float4 wv = *(const float4*)(W1 + (size_t)col * K + k0 + lk);
      W1s[lk+0][lr] = wv.x; W1s[lk+1][lr] = wv.y;
      W1s[lk+2][lr] = wv.z; W1s[lk+3][lr] = wv.w;
      if constexpr (DUAL) {
        float4 w2 = *(const float4*)(W2 + (size_t)col * K + k0 + lk);
        W2s[lk+0][lr] = w2.x; W2s[lk+1][lr] = w2.y;
        W2s[lk+2][lr] = w2.z; W2s[lk+3][lr] = w2.w;
      }
    }
    __syncthreads();
    #pragma unroll
    for (int kk = 0; kk < 16; ++kk) {
      float4 a = *(const float4*)&As[kk][ty * 4];
      float4 b = *(const float4*)&W1s[kk][tx * 4];
      float aa[4] = {a.x, a.y, a.z, a.w};
      float bb[4] = {b.x, b.y, b.z, b.w};
      #pragma unroll
      for (int i = 0; i < 4; ++i)
        #pragma unroll
        for (int j = 0; j < 4; ++j)
          acc1[i][j] = fmaf(aa[i], bb[j], acc1[i][j]);
      if constexpr (DUAL) {
        float4 b2 = *(const float4*)&W2s[kk][tx * 4];
        float cc[4] = {b2.x, b2.y, b2.z, b2.w};
        #pragma unroll
        for (int i = 0; i < 4; ++i)
          #pragma unroll
          for (int j = 0; j < 4; ++j)
            acc2[i][j] = fmaf(aa[i], cc[j], acc2[i][j]);
      }
    }
    __syncthreads();
  }

  // ---- epilogue + store (ushort4 per row)
  #pragma unroll
  for (int i = 0; i < 4; ++i) {
    int m = m0 + ty * 4 + i;
    int n = n0 + tx * 4;
    u16 o1[4], o2[4];
    #pragma unroll
    for (int j = 0; j < 4; ++j) {
      float v = acc1[i][j];
      if constexpr (MODE == 0) {
        o1[j] = f2bf(v);
      } else if constexpr (MODE == 2) {
        v += bias[n + j];
        o1[j] = f2bf(1.f / (1.f + expf(v)));      // exp(-softplus(z)) = sigmoid(-z)
      } else if constexpr (MODE == 3) {
        o1[j] = f2bf(1.f / (1.f + expf(-v)));
        o2[j] = f2bf(1.f / (1.f + expf(-acc2[i][j])));
      } else if constexpr (MODE == 4) {
        o1[j] = f2bf(v * acc2[i][j]);
      }
    }
    ushort4 s1; s1.x = o1[0]; s1.y = o1[1]; s1.z = o1[2]; s1.w = o1[3];
    *(ushort4*)(C1 + (size_t)m * N + n) = s1;
    if constexpr (MODE == 3) {
      ushort4 s2; s2.x = o2[0]; s2.y = o2[1]; s2.z = o2[2]; s2.w = o2[3];
      *(ushort4*)(C2 + (size_t)m * N + n) = s2;
    }
  }
}

// ---------------------------------------------------------------
// Sequential recurrence over L. grid = B*H = 80 blocks, 256 thr.
// thread t: d = t&63, sg = t>>6 (16 s values each). state in regs.
// out_inner written IN PLACE over kv buffer.
// ---------------------------------------------------------------
__global__ __launch_bounds__(256) void recur_kernel(
    const u16* __restrict__ wdec, const u16* __restrict__ proj,
    const u16* __restrict__ rr,  const u16* __restrict__ gg,
    u16* __restrict__ kvio, float* __restrict__ fstate) {
  int b = blockIdx.x / NH, h = blockIdx.x % NH;
  int t = threadIdx.x;
  int d = t & 63, sg = t >> 6;
  __shared__ float sw[64], sB[64], sC[64], skv[64], spart[256];
  float st[16];
  #pragma unroll
  for (int i = 0; i < 16; ++i) st[i] = 0.f;

  for (int l = 0; l < LL; ++l) {
    size_t blh = (size_t)(b * LL + l);
    if (sg == 0)      sw[d]  = bf2f(wdec[blh * DIM + h * 64 + d]);
    else if (sg == 1) sB[d]  = bf2f(proj[blh * NPROJ + h * 192 + 64 + d]);
    else if (sg == 2) sC[d]  = bf2f(proj[blh * NPROJ + h * 192 + 128 + d]);
    else              skv[d] = bf2f(kvio[blh * DIM + h * 64 + d]);
    __syncthreads();
    float kvd = skv[d];
    float ps = 0.f;
    #pragma unroll
    for (int i = 0; i < 16; ++i) {
      int s = sg * 16 + i;
      st[i] = fmaf(sw[s], st[i], sB[s] * kvd);
      ps = fmaf(st[i], sC[s], ps);
    }
    spart[t] = ps;
    __syncthreads();
    if (t < 64) {
      float y = spart[d] + spart[64 + d] + spart[128 + d] + spart[192 + d];
      size_t idx = blh * DIM + h * 64 + d;
      kvio[idx] = f2bf(bf2f(rr[idx]) * y * bf2f(gg[idx]));
    }
    __syncthreads();
  }
  #pragma unroll
  for (int i = 0; i < 16; ++i) {
    int s = sg * 16 + i;
    fstate[(((size_t)b * NH + h) * SD + s) * HDD + d] = st[i];
  }
}

// ---------------------------------------------------------------
extern "C" void kernel_launch(void* const* d_in, const int* in_sizes, int n_in,
                              void* d_out, int out_size, void* d_ws, size_t ws_size,
                              hipStream_t stream) {
  const float* x    = (const float*)d_in[0];
  const float* W_r  = (const float*)d_in[1];
  const float* W_k  = (const float*)d_in[2];
  const float* W_v  = (const float*)d_in[3];
  const float* W_g  = (const float*)d_in[4];
  const float* W_xp = (const float*)d_in[5];
  const float* W_dt = (const float*)d_in[6];
  const float* b_dt = (const float*)d_in[7];
  const float* cw   = (const float*)d_in[8];
  const float* ln1g = (const float*)d_in[9];
  const float* ln1b = (const float*)d_in[10];
  const float* ln2g = (const float*)d_in[11];
  const float* ln2b = (const float*)d_in[12];
  const float* W_o  = (const float*)d_in[13];

  float* out    = (float*)d_out;
  float* fstate = out + (size_t)MTOT * DIM;

  const size_t nBL = (size_t)MTOT * DIM;        // 10.5M elems
  const size_t nPJ = (size_t)MTOT * NPROJ;      // 31.5M elems
  const size_t needed = (nBL * 5 + nPJ) * sizeof(u16);   // ~168 MB
  if (ws_size < needed) {
    // diagnostic: distinctive absmax instead of a page-fault abort
    fill_kernel<<<(out_size + 255) / 256, 256, 0, stream>>>(out, out_size, 1234.5f);
    return;
  }

  u16* ws = (u16*)d_ws;
  u16* x1   = ws;             // bf16, alive to end
  u16* proj = x1 + nBL;       // bf16, alive until recurrence
  u16* wdec = proj + nPJ;     // bf16, reused for y2 after recurrence
  u16* rb   = wdec + nBL;
  u16* gb   = rb + nBL;
  u16* kvb  = gb + nBL;       // kv -> out_inner in place

  // 1. conv + LN1 -> x1 (bf16)
  conv_ln1_kernel<<<MTOT, 256, 0, stream>>>(x, cw, ln1g, ln1b, x1);
  // 2. proj = x1 @ W_xproj^T
  gemm_bt<0,false><<<dim3(NPROJ/64, MTOT/64), 256, 0, stream>>>(x1, W_xp, nullptr, nullptr, proj, nullptr, NPROJ, DIM);
  // 3. w = exp(-softplus(gather(proj) @ W_dt^T + b_dt))
  gemm_bt<2,true ><<<dim3(DIM/64, MTOT/64), 256, 0, stream>>>(proj, W_dt, nullptr, b_dt, wdec, nullptr, DIM, DIM);
  // 4. r,g dual
  gemm_bt<3,false><<<dim3(DIM/64, MTOT/64), 256, 0, stream>>>(x1, W_r, W_g, nullptr, rb, gb, DIM, DIM);
  // 5. kv dual: kv = (x1@W_k^T) * (x1@W_v^T)
  gemm_bt<4,false><<<dim3(DIM/64, MTOT/64), 256, 0, stream>>>(x1, W_k, W_v, nullptr, kvb, nullptr, DIM, DIM);
  // 6. recurrence: out_inner into kvb (in place), final_state into d_out tail
  recur_kernel<<<BB * NH, 256, 0, stream>>>(wdec, proj, rb, gb, kvb, fstate);
  // 7. y2 = out_inner @ W_out^T -> wdec (reuse)
  gemm_bt<0,false><<<dim3(DIM/64, MTOT/64), 256, 0, stream>>>(kvb, W_o, nullptr, nullptr, wdec, nullptr, DIM, DIM);
  // 8. out = LN(x1 + y2) -> fp32
  ln2_kernel<<<MTOT, 256, 0, stream>>>(x1, wdec, ln2g, ln2b, out);
}

// Round 3
// 3016.604 us; speedup vs baseline: 2.8570x; 2.8570x over previous
//
#include <hip/hip_runtime.h>
#include <cstddef>
#include <cstdint>

#define DIM 2560
#define NH 40
#define HDD 64
#define SD 64
#define KC 4
#define BB 2
#define LL 2048
#define MTOT (BB*LL)      // 4096
#define NPROJ (NH*3*SD)   // 7680

typedef unsigned short u16;
typedef __attribute__((ext_vector_type(8))) short bf16x8;
typedef __attribute__((ext_vector_type(4))) float f32x4;

__device__ inline float bf2f(u16 u) { return __uint_as_float(((unsigned)u) << 16); }
__device__ inline u16 f2bf(float f) {
  unsigned x = __float_as_uint(f);
  unsigned r = (x + 0x7fffu + ((x >> 16) & 1u)) >> 16;   // RNE
  return (u16)r;
}

__device__ inline void gload16(const void* g, void* lds) {
  __builtin_amdgcn_global_load_lds(
      (const __attribute__((address_space(1))) void*)g,
      (__attribute__((address_space(3))) void*)(uint32_t)(size_t)lds,
      16, 0, 0);
}

// ---------------------------------------------------------------
// fp32 -> bf16 convert (weights), vectorized
// ---------------------------------------------------------------
__global__ __launch_bounds__(256) void cvt_kernel(
    const float* __restrict__ src, u16* __restrict__ dst, int n4) {
  int i = blockIdx.x * 256 + threadIdx.x;
  int stride = gridDim.x * 256;
  for (; i < n4; i += stride) {
    float4 v = *(const float4*)(src + (size_t)i * 4);
    ushort4 o;
    o.x = f2bf(v.x); o.y = f2bf(v.y); o.z = f2bf(v.z); o.w = f2bf(v.w);
    *(ushort4*)(dst + (size_t)i * 4) = o;
  }
}

// ---------------------------------------------------------------
__global__ __launch_bounds__(256) void fill_kernel(float* p, int n, float v) {
  int i = blockIdx.x * 256 + threadIdx.x;
  if (i < n) p[i] = v;
}

// ---------------------------------------------------------------
__device__ inline void block_reduce2(float& sum, float& sq, float* red) {
  #pragma unroll
  for (int off = 32; off; off >>= 1) {
    sum += __shfl_down(sum, off, 64);
    sq  += __shfl_down(sq,  off, 64);
  }
  int wid = threadIdx.x >> 6, lane = threadIdx.x & 63;
  if (lane == 0) { red[wid*2] = sum; red[wid*2+1] = sq; }
  __syncthreads();
  sum = red[0] + red[2] + red[4] + red[6];
  sq  = red[1] + red[3] + red[5] + red[7];
}

// ---------------------------------------------------------------
// conv (causal depthwise, K=4) + residual + LayerNorm1 -> bf16
// ---------------------------------------------------------------
__global__ __launch_bounds__(256) void conv_ln1_kernel(
    const float* __restrict__ x, const float* __restrict__ cw,
    const float* __restrict__ g1, const float* __restrict__ b1,
    u16* __restrict__ x1) {
  __shared__ float red[8];
  int bl = blockIdx.x;
  int l  = bl & (LL - 1);
  int t  = threadIdx.x;
  const float* xr = x + (size_t)bl * DIM;
  float vals[10];
  float sum = 0.f, sq = 0.f;
  #pragma unroll
  for (int i = 0; i < 10; ++i) {
    int d = t + 256 * i;
    float acc = xr[d];
    #pragma unroll
    for (int j = 0; j < KC; ++j) {
      int ll = l - (KC - 1) + j;
      if (ll >= 0) acc += x[(size_t)(bl - l + ll) * DIM + d] * cw[d * KC + j];
    }
    vals[i] = acc; sum += acc; sq += acc * acc;
  }
  block_reduce2(sum, sq, red);
  float mean = sum * (1.f / DIM);
  float var  = sq * (1.f / DIM) - mean * mean;
  float rstd = rsqrtf(var + 1e-5f);
  u16* orow = x1 + (size_t)bl * DIM;
  #pragma unroll
  for (int i = 0; i < 10; ++i) {
    int d = t + 256 * i;
    orow[d] = f2bf((vals[i] - mean) * rstd * g1[d] + b1[d]);
  }
}

// ---------------------------------------------------------------
// LN2: out = LN(x1 + y2), bf16 inputs -> fp32 out
// ---------------------------------------------------------------
__global__ __launch_bounds__(256) void ln2_kernel(
    const u16* __restrict__ x1, const u16* __restrict__ y2,
    const float* __restrict__ g2, const float* __restrict__ b2,
    float* __restrict__ out) {
  __shared__ float red[8];
  int bl = blockIdx.x;
  int t  = threadIdx.x;
  const u16* ar = x1 + (size_t)bl * DIM;
  const u16* br = y2 + (size_t)bl * DIM;
  float vals[10];
  float sum = 0.f, sq = 0.f;
  #pragma unroll
  for (int i = 0; i < 10; ++i) {
    int d = t + 256 * i;
    float v = bf2f(ar[d]) + bf2f(br[d]);
    vals[i] = v; sum += v; sq += v * v;
  }
  block_reduce2(sum, sq, red);
  float mean = sum * (1.f / DIM);
  float var  = sq * (1.f / DIM) - mean * mean;
  float rstd = rsqrtf(var + 1e-5f);
  float* orow = out + (size_t)bl * DIM;
  #pragma unroll
  for (int i = 0; i < 10; ++i) {
    int d = t + 256 * i;
    orow[d] = (vals[i] - mean) * rstd * g2[d] + b2[d];
  }
}

// ---------------------------------------------------------------
// MFMA bf16 GEMM (m97 structure): C[M,N] = epi(A[M,K] @ W[N,K]^T)
// 128x128 tile, BK=32, 256 threads (4 waves, 2x2), 4x4 frags/wave.
// global_load_lds(16B) staging, ds_read_b128 fragments.
// EPI: 0 plain | 1 sigmoid | 2 decay sigmoid(-(v+bias)) | 5 C *= acc (kv)
// REMAP: xproj column remap n -> (n%192)/64*2560 + (n/192)*64 + n%64
// ---------------------------------------------------------------
template<int EPI, bool REMAP>
__global__ __launch_bounds__(256) void gemm_mfma(
    const u16* __restrict__ A, int lda,
    const u16* __restrict__ Wb,
    const float* __restrict__ bias,
    u16* __restrict__ C1, int ldc,
    int K) {
  __shared__ u16 As[128 * 32];
  __shared__ u16 Bs[128 * 32];
  int t = threadIdx.x;
  int w = t >> 6, l = t & 63;
  int wr = w >> 1, wc = w & 1;
  int m0 = blockIdx.y * 128;
  int n0 = blockIdx.x * 128;

  f32x4 acc[4][4];
  #pragma unroll
  for (int i = 0; i < 4; ++i)
    #pragma unroll
    for (int j = 0; j < 4; ++j)
      acc[i][j] = (f32x4){0.f, 0.f, 0.f, 0.f};

  // staging source addresses (per-lane): 16 rows x 32 cols per wave-call
  int srow = 32 * w + (l >> 2);
  int scol = (l & 3) * 8;
  const u16* gA = A  + (size_t)(m0 + srow) * lda + scol;
  const u16* gB = Wb + (size_t)(n0 + srow) * K   + scol;
  u16* ldsA = As + (32 * w) * 32;   // wave-uniform LDS dest
  u16* ldsB = Bs + (32 * w) * 32;

  // fragment read addresses
  int fr = l & 15;                   // row within 16x16
  int kc = (l >> 4) * 8;             // k offset (8 contiguous bf16)
  const u16* rA = As + (size_t)(wr * 64 + fr) * 32 + kc;
  const u16* rB = Bs + (size_t)(wc * 64 + fr) * 32 + kc;

  for (int k0 = 0; k0 < K; k0 += 32) {
    gload16(gA + k0, ldsA);
    gload16(gA + (size_t)16 * lda + k0, ldsA + 16 * 32);
    gload16(gB + k0, ldsB);
    gload16(gB + (size_t)16 * K + k0, ldsB + 16 * 32);
    __syncthreads();                 // drains vmcnt before barrier
    bf16x8 a[4], b[4];
    #pragma unroll
    for (int i = 0; i < 4; ++i) a[i] = *(const bf16x8*)(rA + i * 16 * 32);
    #pragma unroll
    for (int j = 0; j < 4; ++j) b[j] = *(const bf16x8*)(rB + j * 16 * 32);
    #pragma unroll
    for (int i = 0; i < 4; ++i)
      #pragma unroll
      for (int j = 0; j < 4; ++j)
        acc[i][j] = __builtin_amdgcn_mfma_f32_16x16x32_bf16(a[i], b[j], acc[i][j], 0, 0, 0);
    __syncthreads();
  }

  // epilogue: C/D mapping col = lane&15, row = (lane>>4)*4 + q  [m89-verified]
  int crow = (l >> 4) * 4;
  int ccol = l & 15;
  #pragma unroll
  for (int j = 0; j < 4; ++j) {
    int col = n0 + wc * 64 + j * 16 + ccol;
    int colr = col;
    if (REMAP) {
      int h = col / 192, r3 = col % 192;
      colr = (r3 / 64) * 2560 + h * 64 + (r3 & 63);
    }
    float bv = (EPI == 2) ? bias[col] : 0.f;
    #pragma unroll
    for (int i = 0; i < 4; ++i) {
      #pragma unroll
      for (int q = 0; q < 4; ++q) {
        int row = m0 + wr * 64 + i * 16 + crow + q;
        float v = acc[i][j][q];
        if constexpr (EPI == 1) v = 1.f / (1.f + expf(-v));
        if constexpr (EPI == 2) v = 1.f / (1.f + expf(v + bv));  // exp(-softplus)
        size_t idx = (size_t)row * ldc + colr;
        if constexpr (EPI == 5) v *= bf2f(C1[idx]);
        C1[idx] = f2bf(v);
      }
    }
  }
}

// ---------------------------------------------------------------
// Sequential recurrence. grid = B*H = 80, 256 threads.
// proj layout: [dt(2560) | B(2560) | C(2560)] per row.
// ---------------------------------------------------------------
__global__ __launch_bounds__(256) void recur_kernel(
    const u16* __restrict__ wdec, const u16* __restrict__ proj,
    const u16* __restrict__ rr,  const u16* __restrict__ gg,
    u16* __restrict__ kvio, float* __restrict__ fstate) {
  int b = blockIdx.x / NH, h = blockIdx.x % NH;
  int t = threadIdx.x;
  int d = t & 63, sg = t >> 6;
  __shared__ float sw[64], sB[64], sC[64], skv[64], spart[256];
  float st[16];
  #pragma unroll
  for (int i = 0; i < 16; ++i) st[i] = 0.f;

  for (int l = 0; l < LL; ++l) {
    size_t blh = (size_t)(b * LL + l);
    if (sg == 0)      sw[d]  = bf2f(wdec[blh * DIM + h * 64 + d]);
    else if (sg == 1) sB[d]  = bf2f(proj[blh * NPROJ + 2560 + h * 64 + d]);
    else if (sg == 2) sC[d]  = bf2f(proj[blh * NPROJ + 5120 + h * 64 + d]);
    else              skv[d] = bf2f(kvio[blh * DIM + h * 64 + d]);
    __syncthreads();
    float kvd = skv[d];
    float ps = 0.f;
    #pragma unroll
    for (int i = 0; i < 16; ++i) {
      int s = sg * 16 + i;
      st[i] = fmaf(sw[s], st[i], sB[s] * kvd);
      ps = fmaf(st[i], sC[s], ps);
    }
    spart[t] = ps;
    __syncthreads();
    if (t < 64) {
      float y = spart[d] + spart[64 + d] + spart[128 + d] + spart[192 + d];
      size_t idx = blh * DIM + h * 64 + d;
      kvio[idx] = f2bf(bf2f(rr[idx]) * y * bf2f(gg[idx]));
    }
    __syncthreads();
  }
  #pragma unroll
  for (int i = 0; i < 16; ++i) {
    int s = sg * 16 + i;
    fstate[(((size_t)b * NH + h) * SD + s) * HDD + d] = st[i];
  }
}

// ---------------------------------------------------------------
extern "C" void kernel_launch(void* const* d_in, const int* in_sizes, int n_in,
                              void* d_out, int out_size, void* d_ws, size_t ws_size,
                              hipStream_t stream) {
  const float* x    = (const float*)d_in[0];
  const float* W_r  = (const float*)d_in[1];
  const float* W_k  = (const float*)d_in[2];
  const float* W_v  = (const float*)d_in[3];
  const float* W_g  = (const float*)d_in[4];
  const float* W_xp = (const float*)d_in[5];
  const float* W_dt = (const float*)d_in[6];
  const float* b_dt = (const float*)d_in[7];
  const float* cw   = (const float*)d_in[8];
  const float* ln1g = (const float*)d_in[9];
  const float* ln1b = (const float*)d_in[10];
  const float* ln2g = (const float*)d_in[11];
  const float* ln2b = (const float*)d_in[12];
  const float* W_o  = (const float*)d_in[13];

  float* out    = (float*)d_out;
  float* fstate = out + (size_t)MTOT * DIM;

  const size_t nBL = (size_t)MTOT * DIM;         // 10.49M
  const size_t nPJ = (size_t)MTOT * NPROJ;       // 31.46M
  const size_t nWX = (size_t)NPROJ * DIM;        // 19.66M (largest weight)
  const size_t needed = (nBL * 5 + nPJ + nWX) * sizeof(u16);  // ~207 MB
  if (ws_size < needed) {
    fill_kernel<<<(out_size + 255) / 256, 256, 0, stream>>>(out, out_size, 1234.5f);
    return;
  }

  u16* wsp  = (u16*)d_ws;
  u16* x1   = wsp;
  u16* proj = x1 + nBL;
  u16* wdec = proj + nPJ;       // reused for y2 after recurrence
  u16* rb   = wdec + nBL;
  u16* gb   = rb + nBL;
  u16* kvb  = gb + nBL;         // k -> kv -> out_inner in place
  u16* wscr = kvb + nBL;        // rotating bf16 weight scratch

  const int nDD4 = DIM * DIM / 4;

  // 1. conv + LN1 -> x1 (bf16)
  conv_ln1_kernel<<<MTOT, 256, 0, stream>>>(x, cw, ln1g, ln1b, x1);

  // 2. proj = x1 @ W_xproj^T  (REMAP columns to [dt|B|C])
  cvt_kernel<<<2048, 256, 0, stream>>>(W_xp, wscr, NPROJ * DIM / 4);
  gemm_mfma<0,true ><<<dim3(NPROJ/128, MTOT/128), 256, 0, stream>>>(x1, DIM, wscr, nullptr, proj, NPROJ, DIM);

  // 3. w = exp(-softplus(proj_dt @ W_dt^T + b_dt))
  cvt_kernel<<<2048, 256, 0, stream>>>(W_dt, wscr, nDD4);
  gemm_mfma<2,false><<<dim3(DIM/128, MTOT/128), 256, 0, stream>>>(proj, NPROJ, wscr, b_dt, wdec, DIM, DIM);

  // 4. r = sigmoid(x1 @ W_r^T)
  cvt_kernel<<<2048, 256, 0, stream>>>(W_r, wscr, nDD4);
  gemm_mfma<1,false><<<dim3(DIM/128, MTOT/128), 256, 0, stream>>>(x1, DIM, wscr, nullptr, rb, DIM, DIM);

  // 5. g = sigmoid(x1 @ W_g^T)
  cvt_kernel<<<2048, 256, 0, stream>>>(W_g, wscr, nDD4);
  gemm_mfma<1,false><<<dim3(DIM/128, MTOT/128), 256, 0, stream>>>(x1, DIM, wscr, nullptr, gb, DIM, DIM);

  // 6. k = x1 @ W_k^T
  cvt_kernel<<<2048, 256, 0, stream>>>(W_k, wscr, nDD4);
  gemm_mfma<0,false><<<dim3(DIM/128, MTOT/128), 256, 0, stream>>>(x1, DIM, wscr, nullptr, kvb, DIM, DIM);

  // 7. kv = k * (x1 @ W_v^T)   (multiply-into epilogue)
  cvt_kernel<<<2048, 256, 0, stream>>>(W_v, wscr, nDD4);
  gemm_mfma<5,false><<<dim3(DIM/128, MTOT/128), 256, 0, stream>>>(x1, DIM, wscr, nullptr, kvb, DIM, DIM);

  // 8. recurrence
  recur_kernel<<<BB * NH, 256, 0, stream>>>(wdec, proj, rb, gb, kvb, fstate);

  // 9. y2 = out_inner @ W_out^T -> wdec (reuse)
  cvt_kernel<<<2048, 256, 0, stream>>>(W_o, wscr, nDD4);
  gemm_mfma<0,false><<<dim3(DIM/128, MTOT/128), 256, 0, stream>>>(kvb, DIM, wscr, nullptr, wdec, DIM, DIM);

  // 10. out = LN(x1 + y2) -> fp32
  ln2_kernel<<<MTOT, 256, 0, stream>>>(x1, wdec, ln2g, ln2b, out);
}

// Round 5
// 2220.458 us; speedup vs baseline: 3.8813x; 1.3586x over previous
//
#include <hip/hip_runtime.h>
#include <cstddef>
#include <cstdint>

#define DIM 2560
#define NH 40
#define HDD 64
#define SD 64
#define KC 4
#define BB 2
#define LL 2048
#define MTOT (BB*LL)      // 4096
#define NPROJ (NH*3*SD)   // 7680

typedef unsigned short u16;
typedef __attribute__((ext_vector_type(8))) short bf16x8;
typedef __attribute__((ext_vector_type(4))) float f32x4;

__device__ inline float bf2f(u16 u) { return __uint_as_float(((unsigned)u) << 16); }
__device__ inline float bflo(unsigned u) { return __uint_as_float(u << 16); }
__device__ inline float bfhi(unsigned u) { return __uint_as_float(u & 0xffff0000u); }
__device__ inline u16 f2bf(float f) {
  unsigned x = __float_as_uint(f);
  unsigned r = (x + 0x7fffu + ((x >> 16) & 1u)) >> 16;   // RNE
  return (u16)r;
}

__device__ inline void gload16(const void* g, void* lds) {
  __builtin_amdgcn_global_load_lds(
      (const __attribute__((address_space(1))) void*)g,
      (__attribute__((address_space(3))) void*)(uint32_t)(size_t)lds,
      16, 0, 0);
}

// ---------------------------------------------------------------
__global__ __launch_bounds__(256) void cvt_kernel(
    const float* __restrict__ src, u16* __restrict__ dst, int n4) {
  int i = blockIdx.x * 256 + threadIdx.x;
  int stride = gridDim.x * 256;
  for (; i < n4; i += stride) {
    float4 v = *(const float4*)(src + (size_t)i * 4);
    ushort4 o;
    o.x = f2bf(v.x); o.y = f2bf(v.y); o.z = f2bf(v.z); o.w = f2bf(v.w);
    *(ushort4*)(dst + (size_t)i * 4) = o;
  }
}

// ---------------------------------------------------------------
__global__ __launch_bounds__(256) void fill_kernel(float* p, int n, float v) {
  int i = blockIdx.x * 256 + threadIdx.x;
  if (i < n) p[i] = v;
}

// ---------------------------------------------------------------
__device__ inline void block_reduce2(float& sum, float& sq, float* red) {
  #pragma unroll
  for (int off = 32; off; off >>= 1) {
    sum += __shfl_down(sum, off, 64);
    sq  += __shfl_down(sq,  off, 64);
  }
  int wid = threadIdx.x >> 6, lane = threadIdx.x & 63;
  if (lane == 0) { red[wid*2] = sum; red[wid*2+1] = sq; }
  __syncthreads();
  sum = red[0] + red[2] + red[4] + red[6];
  sq  = red[1] + red[3] + red[5] + red[7];
}

// ---------------------------------------------------------------
// conv (causal depthwise, K=4) + residual + LayerNorm1 -> bf16
// ---------------------------------------------------------------
__global__ __launch_bounds__(256) void conv_ln1_kernel(
    const float* __restrict__ x, const float* __restrict__ cw,
    const float* __restrict__ g1, const float* __restrict__ b1,
    u16* __restrict__ x1) {
  __shared__ float red[8];
  int bl = blockIdx.x;
  int l  = bl & (LL - 1);
  int t  = threadIdx.x;
  const float* xr = x + (size_t)bl * DIM;
  float vals[10];
  float sum = 0.f, sq = 0.f;
  #pragma unroll
  for (int i = 0; i < 10; ++i) {
    int d = t + 256 * i;
    float acc = xr[d];
    #pragma unroll
    for (int j = 0; j < KC; ++j) {
      int ll = l - (KC - 1) + j;
      if (ll >= 0) acc += x[(size_t)(bl - l + ll) * DIM + d] * cw[d * KC + j];
    }
    vals[i] = acc; sum += acc; sq += acc * acc;
  }
  block_reduce2(sum, sq, red);
  float mean = sum * (1.f / DIM);
  float var  = sq * (1.f / DIM) - mean * mean;
  float rstd = rsqrtf(var + 1e-5f);
  u16* orow = x1 + (size_t)bl * DIM;
  #pragma unroll
  for (int i = 0; i < 10; ++i) {
    int d = t + 256 * i;
    orow[d] = f2bf((vals[i] - mean) * rstd * g1[d] + b1[d]);
  }
}

// ---------------------------------------------------------------
// LN2: out = LN(x1 + y2), bf16 inputs -> fp32 out
// ---------------------------------------------------------------
__global__ __launch_bounds__(256) void ln2_kernel(
    const u16* __restrict__ x1, const u16* __restrict__ y2,
    const float* __restrict__ g2, const float* __restrict__ b2,
    float* __restrict__ out) {
  __shared__ float red[8];
  int bl = blockIdx.x;
  int t  = threadIdx.x;
  const u16* ar = x1 + (size_t)bl * DIM;
  const u16* br = y2 + (size_t)bl * DIM;
  float vals[10];
  float sum = 0.f, sq = 0.f;
  #pragma unroll
  for (int i = 0; i < 10; ++i) {
    int d = t + 256 * i;
    float v = bf2f(ar[d]) + bf2f(br[d]);
    vals[i] = v; sum += v; sq += v * v;
  }
  block_reduce2(sum, sq, red);
  float mean = sum * (1.f / DIM);
  float var  = sq * (1.f / DIM) - mean * mean;
  float rstd = rsqrtf(var + 1e-5f);
  float* orow = out + (size_t)bl * DIM;
  #pragma unroll
  for (int i = 0; i < 10; ++i) {
    int d = t + 256 * i;
    orow[d] = (vals[i] - mean) * rstd * g2[d] + b2[d];
  }
}

// ---------------------------------------------------------------
// MFMA bf16 GEMM (m97 structure): C[M,N] = epi(A[M,K] @ W[N,K]^T)
// 128x128 tile, BK=32, 256 threads (4 waves, 2x2), 4x4 frags/wave.
// EPI: 0 plain | 1 sigmoid | 2 decay sigmoid(-(v+bias)) | 5 C *= acc (kv)
// REMAP: xproj column remap n -> (n%192)/64*2560 + (n/192)*64 + n%64
// ---------------------------------------------------------------
template<int EPI, bool REMAP>
__global__ __launch_bounds__(256) void gemm_mfma(
    const u16* __restrict__ A, int lda,
    const u16* __restrict__ Wb,
    const float* __restrict__ bias,
    u16* __restrict__ C1, int ldc,
    int K) {
  __shared__ u16 As[128 * 32];
  __shared__ u16 Bs[128 * 32];
  int t = threadIdx.x;
  int w = t >> 6, l = t & 63;
  int wr = w >> 1, wc = w & 1;
  int m0 = blockIdx.y * 128;
  int n0 = blockIdx.x * 128;

  f32x4 acc[4][4];
  #pragma unroll
  for (int i = 0; i < 4; ++i)
    #pragma unroll
    for (int j = 0; j < 4; ++j)
      acc[i][j] = (f32x4){0.f, 0.f, 0.f, 0.f};

  int srow = 32 * w + (l >> 2);
  int scol = (l & 3) * 8;
  const u16* gA = A  + (size_t)(m0 + srow) * lda + scol;
  const u16* gB = Wb + (size_t)(n0 + srow) * K   + scol;
  u16* ldsA = As + (32 * w) * 32;
  u16* ldsB = Bs + (32 * w) * 32;

  int fr = l & 15;
  int kc = (l >> 4) * 8;
  const u16* rA = As + (size_t)(wr * 64 + fr) * 32 + kc;
  const u16* rB = Bs + (size_t)(wc * 64 + fr) * 32 + kc;

  for (int k0 = 0; k0 < K; k0 += 32) {
    gload16(gA + k0, ldsA);
    gload16(gA + (size_t)16 * lda + k0, ldsA + 16 * 32);
    gload16(gB + k0, ldsB);
    gload16(gB + (size_t)16 * K + k0, ldsB + 16 * 32);
    __syncthreads();
    bf16x8 a[4], b[4];
    #pragma unroll
    for (int i = 0; i < 4; ++i) a[i] = *(const bf16x8*)(rA + i * 16 * 32);
    #pragma unroll
    for (int j = 0; j < 4; ++j) b[j] = *(const bf16x8*)(rB + j * 16 * 32);
    #pragma unroll
    for (int i = 0; i < 4; ++i)
      #pragma unroll
      for (int j = 0; j < 4; ++j)
        acc[i][j] = __builtin_amdgcn_mfma_f32_16x16x32_bf16(a[i], b[j], acc[i][j], 0, 0, 0);
    __syncthreads();
  }

  int crow = (l >> 4) * 4;
  int ccol = l & 15;
  #pragma unroll
  for (int j = 0; j < 4; ++j) {
    int col = n0 + wc * 64 + j * 16 + ccol;
    int colr = col;
    if (REMAP) {
      int h = col / 192, r3 = col % 192;
      colr = (r3 / 64) * 2560 + h * 64 + (r3 & 63);
    }
    float bv = (EPI == 2) ? bias[col] : 0.f;
    #pragma unroll
    for (int i = 0; i < 4; ++i) {
      #pragma unroll
      for (int q = 0; q < 4; ++q) {
        int row = m0 + wr * 64 + i * 16 + crow + q;
        float v = acc[i][j][q];
        if constexpr (EPI == 1) v = 1.f / (1.f + expf(-v));
        if constexpr (EPI == 2) v = 1.f / (1.f + expf(v + bv));
        size_t idx = (size_t)row * ldc + colr;
        if constexpr (EPI == 5) v *= bf2f(C1[idx]);
        C1[idx] = f2bf(v);
      }
    }
  }
}

// ---------------------------------------------------------------
// Barrier-free sequential recurrence.
// grid = B*NH*2 = 160 blocks x 256 threads (4 independent waves).
// wave -> dgrp = half*4 + waveid; lane = 8*sgrp + dd.
// Thread owns st[8] = state[sgrp*8 .. +8][d], d = dgrp*8+dd.
// Inputs prefetched 2 steps ahead into registers; y-reduce via
// 3x shfl_xor over sgrp lanes. y written into proj dt-region (dead).
// ---------------------------------------------------------------
__global__ __launch_bounds__(256) void recur_kernel(
    const u16* __restrict__ wdec, const u16* __restrict__ proj,
    const u16* __restrict__ kvb, u16* __restrict__ yout,
    float* __restrict__ fstate) {
  int bh = blockIdx.x >> 1, half = blockIdx.x & 1;
  int b = bh / NH, h = bh % NH;
  int wv = threadIdx.x >> 6;
  int lane = threadIdx.x & 63;
  int sg = lane >> 3, dd = lane & 7;
  int d = (half * 4 + wv) * 8 + dd;

  const u16* pw = wdec + (size_t)b * LL * DIM + h * 64 + sg * 8;
  const u16* pB = proj + (size_t)b * LL * NPROJ + 2560 + h * 64 + sg * 8;
  const u16* pC = pB + 2560;
  const u16* pk = kvb + (size_t)b * LL * DIM + h * 64 + d;
  u16* py = yout + (size_t)b * LL * NPROJ + h * 64 + d;

  // prefetch pointers (point at step l+2 during iteration l)
  const u16* fw = pw; const u16* fB = pB; const u16* fC = pC; const u16* fk = pk;

  uint4 wA[2], BA[2], CA[2]; u16 kA[2];
  wA[0] = *(const uint4*)fw; BA[0] = *(const uint4*)fB;
  CA[0] = *(const uint4*)fC; kA[0] = *fk;
  fw += DIM; fB += NPROJ; fC += NPROJ; fk += DIM;
  wA[1] = *(const uint4*)fw; BA[1] = *(const uint4*)fB;
  CA[1] = *(const uint4*)fC; kA[1] = *fk;
  fw += DIM; fB += NPROJ; fC += NPROJ; fk += DIM;

  float st[8];
  #pragma unroll
  for (int i = 0; i < 8; ++i) st[i] = 0.f;

  for (int l = 0; l < LL; ++l) {
    int cur = l & 1;
    uint4 wu = wA[cur], Bu = BA[cur], Cu = CA[cur];
    float kvf = bf2f(kA[cur]);

    // issue prefetch for step l+2 into the slot just freed
    wA[cur] = *(const uint4*)fw; BA[cur] = *(const uint4*)fB;
    CA[cur] = *(const uint4*)fC; kA[cur] = *fk;
    if (l + 3 < LL) { fw += DIM; fB += NPROJ; fC += NPROJ; fk += DIM; }

    float p = 0.f;
    float wf, Bf, Cf;
    #define RSTEP(i, word, LH) \
      wf = LH(Bu.word); Bf = wf; wf = LH(wu.word); Cf = LH(Cu.word); \
      st[i] = fmaf(wf, st[i], Bf * kvf); p = fmaf(st[i], Cf, p);
    RSTEP(0, x, bflo) RSTEP(1, x, bfhi)
    RSTEP(2, y, bflo) RSTEP(3, y, bfhi)
    RSTEP(4, z, bflo) RSTEP(5, z, bfhi)
    RSTEP(6, w, bflo) RSTEP(7, w, bfhi)
    #undef RSTEP

    p += __shfl_xor(p, 8, 64);
    p += __shfl_xor(p, 16, 64);
    p += __shfl_xor(p, 32, 64);
    if (lane < 8) *py = f2bf(p);
    py += NPROJ;
  }

  #pragma unroll
  for (int i = 0; i < 8; ++i)
    fstate[(((size_t)b * NH + h) * SD + sg * 8 + i) * HDD + d] = st[i];
}

// ---------------------------------------------------------------
// gate: out_inner = r * y * g   (y in proj dt-region cols 0..2560)
// grid MTOT x 320 threads, 8 elems each (bf16x8 vectorized)
// ---------------------------------------------------------------
__global__ __launch_bounds__(320) void gate_kernel(
    const u16* __restrict__ proj, const u16* __restrict__ rb,
    const u16* __restrict__ gb, u16* __restrict__ outi) {
  int bl = blockIdx.x, t = threadIdx.x;
  uint4 yv = *(const uint4*)(proj + (size_t)bl * NPROJ + t * 8);
  uint4 rv = *(const uint4*)(rb + (size_t)bl * DIM + t * 8);
  uint4 gv = *(const uint4*)(gb + (size_t)bl * DIM + t * 8);
  unsigned yw[4] = {yv.x, yv.y, yv.z, yv.w};
  unsigned rw[4] = {rv.x, rv.y, rv.z, rv.w};
  unsigned gw[4] = {gv.x, gv.y, gv.z, gv.w};
  u16 res[8];
  #pragma unroll
  for (int i = 0; i < 4; ++i) {
    res[2*i]   = f2bf(bflo(yw[i]) * bflo(rw[i]) * bflo(gw[i]));
    res[2*i+1] = f2bf(bfhi(yw[i]) * bfhi(rw[i]) * bfhi(gw[i]));
  }
  uint4 ov;
  ov.x = (unsigned)res[0] | ((unsigned)res[1] << 16);
  ov.y = (unsigned)res[2] | ((unsigned)res[3] << 16);
  ov.z = (unsigned)res[4] | ((unsigned)res[5] << 16);
  ov.w = (unsigned)res[6] | ((unsigned)res[7] << 16);
  *(uint4*)(outi + (size_t)bl * DIM + t * 8) = ov;
}

// ---------------------------------------------------------------
extern "C" void kernel_launch(void* const* d_in, const int* in_sizes, int n_in,
                              void* d_out, int out_size, void* d_ws, size_t ws_size,
                              hipStream_t stream) {
  const float* x    = (const float*)d_in[0];
  const float* W_r  = (const float*)d_in[1];
  const float* W_k  = (const float*)d_in[2];
  const float* W_v  = (const float*)d_in[3];
  const float* W_g  = (const float*)d_in[4];
  const float* W_xp = (const float*)d_in[5];
  const float* W_dt = (const float*)d_in[6];
  const float* b_dt = (const float*)d_in[7];
  const float* cw   = (const float*)d_in[8];
  const float* ln1g = (const float*)d_in[9];
  const float* ln1b = (const float*)d_in[10];
  const float* ln2g = (const float*)d_in[11];
  const float* ln2b = (const float*)d_in[12];
  const float* W_o  = (const float*)d_in[13];

  float* out    = (float*)d_out;
  float* fstate = out + (size_t)MTOT * DIM;

  const size_t nBL = (size_t)MTOT * DIM;
  const size_t nPJ = (size_t)MTOT * NPROJ;
  const size_t nWX = (size_t)NPROJ * DIM;
  const size_t needed = (nBL * 5 + nPJ + nWX) * sizeof(u16);  // ~207 MB
  if (ws_size < needed) {
    fill_kernel<<<(out_size + 255) / 256, 256, 0, stream>>>(out, out_size, 1234.5f);
    return;
  }

  u16* wsp  = (u16*)d_ws;
  u16* x1   = wsp;
  u16* proj = x1 + nBL;
  u16* wdec = proj + nPJ;       // reused for y2 after recurrence
  u16* rb   = wdec + nBL;
  u16* gb   = rb + nBL;
  u16* kvb  = gb + nBL;         // k -> kv; out_inner after gate
  u16* wscr = kvb + nBL;

  const int nDD4 = DIM * DIM / 4;

  // 1. conv + LN1 -> x1 (bf16)
  conv_ln1_kernel<<<MTOT, 256, 0, stream>>>(x, cw, ln1g, ln1b, x1);

  // 2. proj = x1 @ W_xproj^T  (REMAP columns to [dt|B|C])
  cvt_kernel<<<2048, 256, 0, stream>>>(W_xp, wscr, NPROJ * DIM / 4);
  gemm_mfma<0,true ><<<dim3(NPROJ/128, MTOT/128), 256, 0, stream>>>(x1, DIM, wscr, nullptr, proj, NPROJ, DIM);

  // 3. w = exp(-softplus(proj_dt @ W_dt^T + b_dt))
  cvt_kernel<<<2048, 256, 0, stream>>>(W_dt, wscr, nDD4);
  gemm_mfma<2,false><<<dim3(DIM/128, MTOT/128), 256, 0, stream>>>(proj, NPROJ, wscr, b_dt, wdec, DIM, DIM);

  // 4. r = sigmoid(x1 @ W_r^T)
  cvt_kernel<<<2048, 256, 0, stream>>>(W_r, wscr, nDD4);
  gemm_mfma<1,false><<<dim3(DIM/128, MTOT/128), 256, 0, stream>>>(x1, DIM, wscr, nullptr, rb, DIM, DIM);

  // 5. g = sigmoid(x1 @ W_g^T)
  cvt_kernel<<<2048, 256, 0, stream>>>(W_g, wscr, nDD4);
  gemm_mfma<1,false><<<dim3(DIM/128, MTOT/128), 256, 0, stream>>>(x1, DIM, wscr, nullptr, gb, DIM, DIM);

  // 6. k = x1 @ W_k^T
  cvt_kernel<<<2048, 256, 0, stream>>>(W_k, wscr, nDD4);
  gemm_mfma<0,false><<<dim3(DIM/128, MTOT/128), 256, 0, stream>>>(x1, DIM, wscr, nullptr, kvb, DIM, DIM);

  // 7. kv = k * (x1 @ W_v^T)
  cvt_kernel<<<2048, 256, 0, stream>>>(W_v, wscr, nDD4);
  gemm_mfma<5,false><<<dim3(DIM/128, MTOT/128), 256, 0, stream>>>(x1, DIM, wscr, nullptr, kvb, DIM, DIM);

  // 8. recurrence: y into proj dt-region, final_state into d_out tail
  recur_kernel<<<BB * NH * 2, 256, 0, stream>>>(wdec, proj, kvb, proj, fstate);

  // 9. out_inner = r * y * g  -> kvb (reuse)
  gate_kernel<<<MTOT, 320, 0, stream>>>(proj, rb, gb, kvb);

  // 10. y2 = out_inner @ W_out^T -> wdec (reuse)
  cvt_kernel<<<2048, 256, 0, stream>>>(W_o, wscr, nDD4);
  gemm_mfma<0,false><<<dim3(DIM/128, MTOT/128), 256, 0, stream>>>(kvb, DIM, wscr, nullptr, wdec, DIM, DIM);

  // 11. out = LN(x1 + y2) -> fp32
  ln2_kernel<<<MTOT, 256, 0, stream>>>(x1, wdec, ln2g, ln2b, out);
}

// Round 6
// 1377.567 us; speedup vs baseline: 6.2562x; 1.6119x over previous
//
#include <hip/hip_runtime.h>
#include <cstddef>
#include <cstdint>

#define DIM 2560
#define NH 40
#define HDD 64
#define SD 64
#define KC 4
#define BB 2
#define LL 2048
#define MTOT (BB*LL)      // 4096
#define NPROJ (NH*3*SD)   // 7680

typedef unsigned short u16;
typedef __attribute__((ext_vector_type(8))) short bf16x8;
typedef __attribute__((ext_vector_type(4))) float f32x4;

__device__ inline float bf2f(u16 u) { return __uint_as_float(((unsigned)u) << 16); }
__device__ inline float bflo(unsigned u) { return __uint_as_float(u << 16); }
__device__ inline float bfhi(unsigned u) { return __uint_as_float(u & 0xffff0000u); }
__device__ inline u16 f2bf(float f) {
  unsigned x = __float_as_uint(f);
  unsigned r = (x + 0x7fffu + ((x >> 16) & 1u)) >> 16;   // RNE
  return (u16)r;
}

__device__ inline void gload16(const void* g, void* lds) {
  __builtin_amdgcn_global_load_lds(
      (const __attribute__((address_space(1))) void*)g,
      (__attribute__((address_space(3))) void*)(uint32_t)(size_t)lds,
      16, 0, 0);
}

// ---------------------------------------------------------------
__global__ __launch_bounds__(256) void cvt_kernel(
    const float* __restrict__ src, u16* __restrict__ dst, int n4) {
  int i = blockIdx.x * 256 + threadIdx.x;
  int stride = gridDim.x * 256;
  for (; i < n4; i += stride) {
    float4 v = *(const float4*)(src + (size_t)i * 4);
    ushort4 o;
    o.x = f2bf(v.x); o.y = f2bf(v.y); o.z = f2bf(v.z); o.w = f2bf(v.w);
    *(ushort4*)(dst + (size_t)i * 4) = o;
  }
}

// ---------------------------------------------------------------
__global__ __launch_bounds__(256) void fill_kernel(float* p, int n, float v) {
  int i = blockIdx.x * 256 + threadIdx.x;
  if (i < n) p[i] = v;
}

// ---------------------------------------------------------------
__device__ inline void block_reduce2(float& sum, float& sq, float* red) {
  #pragma unroll
  for (int off = 32; off; off >>= 1) {
    sum += __shfl_down(sum, off, 64);
    sq  += __shfl_down(sq,  off, 64);
  }
  int wid = threadIdx.x >> 6, lane = threadIdx.x & 63;
  if (lane == 0) { red[wid*2] = sum; red[wid*2+1] = sq; }
  __syncthreads();
  sum = red[0] + red[2] + red[4] + red[6];
  sq  = red[1] + red[3] + red[5] + red[7];
}

// ---------------------------------------------------------------
// conv (causal depthwise, K=4) + residual + LayerNorm1 -> bf16
// ---------------------------------------------------------------
__global__ __launch_bounds__(256) void conv_ln1_kernel(
    const float* __restrict__ x, const float* __restrict__ cw,
    const float* __restrict__ g1, const float* __restrict__ b1,
    u16* __restrict__ x1) {
  __shared__ float red[8];
  int bl = blockIdx.x;
  int l  = bl & (LL - 1);
  int t  = threadIdx.x;
  const float* xr = x + (size_t)bl * DIM;
  float vals[10];
  float sum = 0.f, sq = 0.f;
  #pragma unroll
  for (int i = 0; i < 10; ++i) {
    int d = t + 256 * i;
    float acc = xr[d];
    #pragma unroll
    for (int j = 0; j < KC; ++j) {
      int ll = l - (KC - 1) + j;
      if (ll >= 0) acc += x[(size_t)(bl - l + ll) * DIM + d] * cw[d * KC + j];
    }
    vals[i] = acc; sum += acc; sq += acc * acc;
  }
  block_reduce2(sum, sq, red);
  float mean = sum * (1.f / DIM);
  float var  = sq * (1.f / DIM) - mean * mean;
  float rstd = rsqrtf(var + 1e-5f);
  u16* orow = x1 + (size_t)bl * DIM;
  #pragma unroll
  for (int i = 0; i < 10; ++i) {
    int d = t + 256 * i;
    orow[d] = f2bf((vals[i] - mean) * rstd * g1[d] + b1[d]);
  }
}

// ---------------------------------------------------------------
// LN2: out = LN(x1 + y2), bf16 inputs -> fp32 out
// ---------------------------------------------------------------
__global__ __launch_bounds__(256) void ln2_kernel(
    const u16* __restrict__ x1, const u16* __restrict__ y2,
    const float* __restrict__ g2, const float* __restrict__ b2,
    float* __restrict__ out) {
  __shared__ float red[8];
  int bl = blockIdx.x;
  int t  = threadIdx.x;
  const u16* ar = x1 + (size_t)bl * DIM;
  const u16* br = y2 + (size_t)bl * DIM;
  float vals[10];
  float sum = 0.f, sq = 0.f;
  #pragma unroll
  for (int i = 0; i < 10; ++i) {
    int d = t + 256 * i;
    float v = bf2f(ar[d]) + bf2f(br[d]);
    vals[i] = v; sum += v; sq += v * v;
  }
  block_reduce2(sum, sq, red);
  float mean = sum * (1.f / DIM);
  float var  = sq * (1.f / DIM) - mean * mean;
  float rstd = rsqrtf(var + 1e-5f);
  float* orow = out + (size_t)bl * DIM;
  #pragma unroll
  for (int i = 0; i < 10; ++i) {
    int d = t + 256 * i;
    orow[d] = (vals[i] - mean) * rstd * g2[d] + b2[d];
  }
}

// ---------------------------------------------------------------
// MFMA bf16 GEMM (m97 structure): C[M,N] = epi(A[M,K] @ W[N,K]^T)
// 128x128 tile, BK=32, 256 threads (4 waves, 2x2), 4x4 frags/wave.
// EPI: 0 plain | 1 sigmoid | 2 decay sigmoid(-(v+bias)) | 5 C *= acc (kv)
// REMAP: xproj column remap n -> (n%192)/64*2560 + (n/192)*64 + n%64
// ---------------------------------------------------------------
template<int EPI, bool REMAP>
__global__ __launch_bounds__(256) void gemm_mfma(
    const u16* __restrict__ A, int lda,
    const u16* __restrict__ Wb,
    const float* __restrict__ bias,
    u16* __restrict__ C1, int ldc,
    int K) {
  __shared__ u16 As[128 * 32];
  __shared__ u16 Bs[128 * 32];
  int t = threadIdx.x;
  int w = t >> 6, l = t & 63;
  int wr = w >> 1, wc = w & 1;
  int m0 = blockIdx.y * 128;
  int n0 = blockIdx.x * 128;

  f32x4 acc[4][4];
  #pragma unroll
  for (int i = 0; i < 4; ++i)
    #pragma unroll
    for (int j = 0; j < 4; ++j)
      acc[i][j] = (f32x4){0.f, 0.f, 0.f, 0.f};

  int srow = 32 * w + (l >> 2);
  int scol = (l & 3) * 8;
  const u16* gA = A  + (size_t)(m0 + srow) * lda + scol;
  const u16* gB = Wb + (size_t)(n0 + srow) * K   + scol;
  u16* ldsA = As + (32 * w) * 32;
  u16* ldsB = Bs + (32 * w) * 32;

  int fr = l & 15;
  int kc = (l >> 4) * 8;
  const u16* rA = As + (size_t)(wr * 64 + fr) * 32 + kc;
  const u16* rB = Bs + (size_t)(wc * 64 + fr) * 32 + kc;

  for (int k0 = 0; k0 < K; k0 += 32) {
    gload16(gA + k0, ldsA);
    gload16(gA + (size_t)16 * lda + k0, ldsA + 16 * 32);
    gload16(gB + k0, ldsB);
    gload16(gB + (size_t)16 * K + k0, ldsB + 16 * 32);
    __syncthreads();
    bf16x8 a[4], b[4];
    #pragma unroll
    for (int i = 0; i < 4; ++i) a[i] = *(const bf16x8*)(rA + i * 16 * 32);
    #pragma unroll
    for (int j = 0; j < 4; ++j) b[j] = *(const bf16x8*)(rB + j * 16 * 32);
    #pragma unroll
    for (int i = 0; i < 4; ++i)
      #pragma unroll
      for (int j = 0; j < 4; ++j)
        acc[i][j] = __builtin_amdgcn_mfma_f32_16x16x32_bf16(a[i], b[j], acc[i][j], 0, 0, 0);
    __syncthreads();
  }

  int crow = (l >> 4) * 4;
  int ccol = l & 15;
  #pragma unroll
  for (int j = 0; j < 4; ++j) {
    int col = n0 + wc * 64 + j * 16 + ccol;
    int colr = col;
    if (REMAP) {
      int h = col / 192, r3 = col % 192;
      colr = (r3 / 64) * 2560 + h * 64 + (r3 & 63);
    }
    float bv = (EPI == 2) ? bias[col] : 0.f;
    #pragma unroll
    for (int i = 0; i < 4; ++i) {
      #pragma unroll
      for (int q = 0; q < 4; ++q) {
        int row = m0 + wr * 64 + i * 16 + crow + q;
        float v = acc[i][j][q];
        if constexpr (EPI == 1) v = 1.f / (1.f + expf(-v));
        if constexpr (EPI == 2) v = 1.f / (1.f + expf(v + bv));
        size_t idx = (size_t)row * ldc + colr;
        if constexpr (EPI == 5) v *= bf2f(C1[idx]);
        C1[idx] = f2bf(v);
      }
    }
  }
}

// ---------------------------------------------------------------
// Barrier-free sequential recurrence, 8-deep NAMED register
// prefetch (no runtime-indexed arrays -> no LDS/scratch demotion).
// grid = B*NH*2 = 160 blocks x 256 threads (4 independent waves).
// wave -> dgrp = half*4 + waveid; lane = 8*sgrp + dd.
// Thread owns st[8] = state[sgrp*8 .. +8][d], d = dgrp*8+dd.
// Tail refills read <=8 rows past each logical buffer; all still
// inside d_ws (next buffer's space), values never consumed.
// ---------------------------------------------------------------
__global__ __launch_bounds__(256) void recur_kernel(
    const u16* __restrict__ wdec, const u16* __restrict__ proj,
    const u16* __restrict__ kvb, u16* __restrict__ yout,
    float* __restrict__ fstate) {
  int bh = blockIdx.x >> 1, half = blockIdx.x & 1;
  int b = bh / NH, h = bh % NH;
  int wv = threadIdx.x >> 6;
  int lane = threadIdx.x & 63;
  int sg = lane >> 3, dd = lane & 7;
  int d = (half * 4 + wv) * 8 + dd;

  const u16* fw = wdec + (size_t)b * LL * DIM + h * 64 + sg * 8;
  const u16* fB = proj + (size_t)b * LL * NPROJ + 2560 + h * 64 + sg * 8;
  const u16* fC = fB + 2560;
  const u16* fk = kvb + (size_t)b * LL * DIM + h * 64 + d;
  u16* py = yout + (size_t)b * LL * NPROJ + h * 64 + d;

  float st[8];
  #pragma unroll
  for (int i = 0; i < 8; ++i) st[i] = 0.f;

#define DECLSET(n) uint4 wS##n, BS##n, CS##n; u16 kS##n
#define LOADSET(n) do { \
    wS##n = *(const uint4*)fw; BS##n = *(const uint4*)fB; \
    CS##n = *(const uint4*)fC; kS##n = *fk; \
    fw += DIM; fB += NPROJ; fC += NPROJ; fk += DIM; } while (0)
#define RS(i, word, LH, n) \
    Bf = LH(BS##n.word); wf = LH(wS##n.word); Cf = LH(CS##n.word); \
    st[i] = fmaf(wf, st[i], Bf * kvf); p = fmaf(st[i], Cf, p);
#define PROCSET(n) do { \
    float kvf = bf2f(kS##n); float p = 0.f; float wf, Bf, Cf; \
    RS(0, x, bflo, n) RS(1, x, bfhi, n) \
    RS(2, y, bflo, n) RS(3, y, bfhi, n) \
    RS(4, z, bflo, n) RS(5, z, bfhi, n) \
    RS(6, w, bflo, n) RS(7, w, bfhi, n) \
    p += __shfl_xor(p, 8, 64); \
    p += __shfl_xor(p, 16, 64); \
    p += __shfl_xor(p, 32, 64); \
    if (lane < 8) *py = f2bf(p); \
    py += NPROJ; } while (0)

  DECLSET(0); DECLSET(1); DECLSET(2); DECLSET(3);
  DECLSET(4); DECLSET(5); DECLSET(6); DECLSET(7);
  LOADSET(0); LOADSET(1); LOADSET(2); LOADSET(3);
  LOADSET(4); LOADSET(5); LOADSET(6); LOADSET(7);

  for (int l = 0; l < LL; l += 8) {
    PROCSET(0); LOADSET(0);
    PROCSET(1); LOADSET(1);
    PROCSET(2); LOADSET(2);
    PROCSET(3); LOADSET(3);
    PROCSET(4); LOADSET(4);
    PROCSET(5); LOADSET(5);
    PROCSET(6); LOADSET(6);
    PROCSET(7); LOADSET(7);
  }
#undef DECLSET
#undef LOADSET
#undef RS
#undef PROCSET

  #pragma unroll
  for (int i = 0; i < 8; ++i)
    fstate[(((size_t)b * NH + h) * SD + sg * 8 + i) * HDD + d] = st[i];
}

// ---------------------------------------------------------------
// gate: out_inner = r * y * g   (y in proj dt-region cols 0..2560)
// grid MTOT x 320 threads, 8 elems each (bf16x8 vectorized)
// ---------------------------------------------------------------
__global__ __launch_bounds__(320) void gate_kernel(
    const u16* __restrict__ proj, const u16* __restrict__ rb,
    const u16* __restrict__ gb, u16* __restrict__ outi) {
  int bl = blockIdx.x, t = threadIdx.x;
  uint4 yv = *(const uint4*)(proj + (size_t)bl * NPROJ + t * 8);
  uint4 rv = *(const uint4*)(rb + (size_t)bl * DIM + t * 8);
  uint4 gv = *(const uint4*)(gb + (size_t)bl * DIM + t * 8);
  unsigned yw[4] = {yv.x, yv.y, yv.z, yv.w};
  unsigned rw[4] = {rv.x, rv.y, rv.z, rv.w};
  unsigned gw[4] = {gv.x, gv.y, gv.z, gv.w};
  u16 res[8];
  #pragma unroll
  for (int i = 0; i < 4; ++i) {
    res[2*i]   = f2bf(bflo(yw[i]) * bflo(rw[i]) * bflo(gw[i]));
    res[2*i+1] = f2bf(bfhi(yw[i]) * bfhi(rw[i]) * bfhi(gw[i]));
  }
  uint4 ov;
  ov.x = (unsigned)res[0] | ((unsigned)res[1] << 16);
  ov.y = (unsigned)res[2] | ((unsigned)res[3] << 16);
  ov.z = (unsigned)res[4] | ((unsigned)res[5] << 16);
  ov.w = (unsigned)res[6] | ((unsigned)res[7] << 16);
  *(uint4*)(outi + (size_t)bl * DIM + t * 8) = ov;
}

// ---------------------------------------------------------------
extern "C" void kernel_launch(void* const* d_in, const int* in_sizes, int n_in,
                              void* d_out, int out_size, void* d_ws, size_t ws_size,
                              hipStream_t stream) {
  const float* x    = (const float*)d_in[0];
  const float* W_r  = (const float*)d_in[1];
  const float* W_k  = (const float*)d_in[2];
  const float* W_v  = (const float*)d_in[3];
  const float* W_g  = (const float*)d_in[4];
  const float* W_xp = (const float*)d_in[5];
  const float* W_dt = (const float*)d_in[6];
  const float* b_dt = (const float*)d_in[7];
  const float* cw   = (const float*)d_in[8];
  const float* ln1g = (const float*)d_in[9];
  const float* ln1b = (const float*)d_in[10];
  const float* ln2g = (const float*)d_in[11];
  const float* ln2b = (const float*)d_in[12];
  const float* W_o  = (const float*)d_in[13];

  float* out    = (float*)d_out;
  float* fstate = out + (size_t)MTOT * DIM;

  const size_t nBL = (size_t)MTOT * DIM;
  const size_t nPJ = (size_t)MTOT * NPROJ;
  const size_t nWX = (size_t)NPROJ * DIM;
  const size_t needed = (nBL * 5 + nPJ + nWX) * sizeof(u16);  // ~207 MB
  if (ws_size < needed) {
    fill_kernel<<<(out_size + 255) / 256, 256, 0, stream>>>(out, out_size, 1234.5f);
    return;
  }

  u16* wsp  = (u16*)d_ws;
  u16* x1   = wsp;
  u16* proj = x1 + nBL;
  u16* wdec = proj + nPJ;       // reused for y2 after recurrence
  u16* rb   = wdec + nBL;
  u16* gb   = rb + nBL;
  u16* kvb  = gb + nBL;         // k -> kv; out_inner after gate
  u16* wscr = kvb + nBL;

  const int nDD4 = DIM * DIM / 4;

  // 1. conv + LN1 -> x1 (bf16)
  conv_ln1_kernel<<<MTOT, 256, 0, stream>>>(x, cw, ln1g, ln1b, x1);

  // 2. proj = x1 @ W_xproj^T  (REMAP columns to [dt|B|C])
  cvt_kernel<<<2048, 256, 0, stream>>>(W_xp, wscr, NPROJ * DIM / 4);
  gemm_mfma<0,true ><<<dim3(NPROJ/128, MTOT/128), 256, 0, stream>>>(x1, DIM, wscr, nullptr, proj, NPROJ, DIM);

  // 3. w = exp(-softplus(proj_dt @ W_dt^T + b_dt))
  cvt_kernel<<<2048, 256, 0, stream>>>(W_dt, wscr, nDD4);
  gemm_mfma<2,false><<<dim3(DIM/128, MTOT/128), 256, 0, stream>>>(proj, NPROJ, wscr, b_dt, wdec, DIM, DIM);

  // 4. r = sigmoid(x1 @ W_r^T)
  cvt_kernel<<<2048, 256, 0, stream>>>(W_r, wscr, nDD4);
  gemm_mfma<1,false><<<dim3(DIM/128, MTOT/128), 256, 0, stream>>>(x1, DIM, wscr, nullptr, rb, DIM, DIM);

  // 5. g = sigmoid(x1 @ W_g^T)
  cvt_kernel<<<2048, 256, 0, stream>>>(W_g, wscr, nDD4);
  gemm_mfma<1,false><<<dim3(DIM/128, MTOT/128), 256, 0, stream>>>(x1, DIM, wscr, nullptr, gb, DIM, DIM);

  // 6. k = x1 @ W_k^T
  cvt_kernel<<<2048, 256, 0, stream>>>(W_k, wscr, nDD4);
  gemm_mfma<0,false><<<dim3(DIM/128, MTOT/128), 256, 0, stream>>>(x1, DIM, wscr, nullptr, kvb, DIM, DIM);

  // 7. kv = k * (x1 @ W_v^T)
  cvt_kernel<<<2048, 256, 0, stream>>>(W_v, wscr, nDD4);
  gemm_mfma<5,false><<<dim3(DIM/128, MTOT/128), 256, 0, stream>>>(x1, DIM, wscr, nullptr, kvb, DIM, DIM);

  // 8. recurrence: y into proj dt-region, final_state into d_out tail
  recur_kernel<<<BB * NH * 2, 256, 0, stream>>>(wdec, proj, kvb, proj, fstate);

  // 9. out_inner = r * y * g  -> kvb (reuse)
  gate_kernel<<<MTOT, 320, 0, stream>>>(proj, rb, gb, kvb);

  // 10. y2 = out_inner @ W_out^T -> wdec (reuse)
  cvt_kernel<<<2048, 256, 0, stream>>>(W_o, wscr, nDD4);
  gemm_mfma<0,false><<<dim3(DIM/128, MTOT/128), 256, 0, stream>>>(kvb, DIM, wscr, nullptr, wdec, DIM, DIM);

  // 11. out = LN(x1 + y2) -> fp32
  ln2_kernel<<<MTOT, 256, 0, stream>>>(x1, wdec, ln2g, ln2b, out);
}

// Round 7
// 1085.400 us; speedup vs baseline: 7.9402x; 1.2692x over previous
//
#include <hip/hip_runtime.h>
#include <cstddef>
#include <cstdint>

#define DIM 2560
#define NH 40
#define HDD 64
#define SD 64
#define KC 4
#define BB 2
#define LL 2048
#define MTOT (BB*LL)      // 4096
#define NPROJ (NH*3*SD)   // 7680
#define NC 16             // scan chunks
#define CH (LL/NC)        // 128 steps per chunk
#define BH (BB*NH)        // 80

typedef unsigned short u16;
typedef __attribute__((ext_vector_type(8))) short bf16x8;
typedef __attribute__((ext_vector_type(4))) float f32x4;

__device__ inline float bf2f(u16 u) { return __uint_as_float(((unsigned)u) << 16); }
__device__ inline float bflo(unsigned u) { return __uint_as_float(u << 16); }
__device__ inline float bfhi(unsigned u) { return __uint_as_float(u & 0xffff0000u); }
__device__ inline u16 f2bf(float f) {
  unsigned x = __float_as_uint(f);
  unsigned r = (x + 0x7fffu + ((x >> 16) & 1u)) >> 16;   // RNE
  return (u16)r;
}

__device__ inline void gload16(const void* g, void* lds) {
  __builtin_amdgcn_global_load_lds(
      (const __attribute__((address_space(1))) void*)g,
      (__attribute__((address_space(3))) void*)(uint32_t)(size_t)lds,
      16, 0, 0);
}

// ---------------------------------------------------------------
__global__ __launch_bounds__(256) void cvt_kernel(
    const float* __restrict__ src, u16* __restrict__ dst, int n4) {
  int i = blockIdx.x * 256 + threadIdx.x;
  int stride = gridDim.x * 256;
  for (; i < n4; i += stride) {
    float4 v = *(const float4*)(src + (size_t)i * 4);
    ushort4 o;
    o.x = f2bf(v.x); o.y = f2bf(v.y); o.z = f2bf(v.z); o.w = f2bf(v.w);
    *(ushort4*)(dst + (size_t)i * 4) = o;
  }
}

// ---------------------------------------------------------------
__global__ __launch_bounds__(256) void fill_kernel(float* p, int n, float v) {
  int i = blockIdx.x * 256 + threadIdx.x;
  if (i < n) p[i] = v;
}

// ---------------------------------------------------------------
__device__ inline void block_reduce2(float& sum, float& sq, float* red) {
  #pragma unroll
  for (int off = 32; off; off >>= 1) {
    sum += __shfl_down(sum, off, 64);
    sq  += __shfl_down(sq,  off, 64);
  }
  int wid = threadIdx.x >> 6, lane = threadIdx.x & 63;
  if (lane == 0) { red[wid*2] = sum; red[wid*2+1] = sq; }
  __syncthreads();
  sum = red[0] + red[2] + red[4] + red[6];
  sq  = red[1] + red[3] + red[5] + red[7];
}

// ---------------------------------------------------------------
// conv (causal depthwise, K=4) + residual + LayerNorm1 -> bf16
// ---------------------------------------------------------------
__global__ __launch_bounds__(256) void conv_ln1_kernel(
    const float* __restrict__ x, const float* __restrict__ cw,
    const float* __restrict__ g1, const float* __restrict__ b1,
    u16* __restrict__ x1) {
  __shared__ float red[8];
  int bl = blockIdx.x;
  int l  = bl & (LL - 1);
  int t  = threadIdx.x;
  const float* xr = x + (size_t)bl * DIM;
  float vals[10];
  float sum = 0.f, sq = 0.f;
  #pragma unroll
  for (int i = 0; i < 10; ++i) {
    int d = t + 256 * i;
    float acc = xr[d];
    #pragma unroll
    for (int j = 0; j < KC; ++j) {
      int ll = l - (KC - 1) + j;
      if (ll >= 0) acc += x[(size_t)(bl - l + ll) * DIM + d] * cw[d * KC + j];
    }
    vals[i] = acc; sum += acc; sq += acc * acc;
  }
  block_reduce2(sum, sq, red);
  float mean = sum * (1.f / DIM);
  float var  = sq * (1.f / DIM) - mean * mean;
  float rstd = rsqrtf(var + 1e-5f);
  u16* orow = x1 + (size_t)bl * DIM;
  #pragma unroll
  for (int i = 0; i < 10; ++i) {
    int d = t + 256 * i;
    orow[d] = f2bf((vals[i] - mean) * rstd * g1[d] + b1[d]);
  }
}

// ---------------------------------------------------------------
// LN2: out = LN(x1 + y2), bf16 inputs -> fp32 out
// ---------------------------------------------------------------
__global__ __launch_bounds__(256) void ln2_kernel(
    const u16* __restrict__ x1, const u16* __restrict__ y2,
    const float* __restrict__ g2, const float* __restrict__ b2,
    float* __restrict__ out) {
  __shared__ float red[8];
  int bl = blockIdx.x;
  int t  = threadIdx.x;
  const u16* ar = x1 + (size_t)bl * DIM;
  const u16* br = y2 + (size_t)bl * DIM;
  float vals[10];
  float sum = 0.f, sq = 0.f;
  #pragma unroll
  for (int i = 0; i < 10; ++i) {
    int d = t + 256 * i;
    float v = bf2f(ar[d]) + bf2f(br[d]);
    vals[i] = v; sum += v; sq += v * v;
  }
  block_reduce2(sum, sq, red);
  float mean = sum * (1.f / DIM);
  float var  = sq * (1.f / DIM) - mean * mean;
  float rstd = rsqrtf(var + 1e-5f);
  float* orow = out + (size_t)bl * DIM;
  #pragma unroll
  for (int i = 0; i < 10; ++i) {
    int d = t + 256 * i;
    orow[d] = (vals[i] - mean) * rstd * g2[d] + b2[d];
  }
}

// ---------------------------------------------------------------
// MFMA bf16 GEMM (m97 structure): C[M,N] = epi(A[M,K] @ W[N,K]^T)
// EPI: 0 plain | 1 sigmoid | 2 decay sigmoid(-(v+bias)) | 5 C *= acc
// ---------------------------------------------------------------
template<int EPI, bool REMAP>
__global__ __launch_bounds__(256) void gemm_mfma(
    const u16* __restrict__ A, int lda,
    const u16* __restrict__ Wb,
    const float* __restrict__ bias,
    u16* __restrict__ C1, int ldc,
    int K) {
  __shared__ u16 As[128 * 32];
  __shared__ u16 Bs[128 * 32];
  int t = threadIdx.x;
  int w = t >> 6, l = t & 63;
  int wr = w >> 1, wc = w & 1;
  int m0 = blockIdx.y * 128;
  int n0 = blockIdx.x * 128;

  f32x4 acc[4][4];
  #pragma unroll
  for (int i = 0; i < 4; ++i)
    #pragma unroll
    for (int j = 0; j < 4; ++j)
      acc[i][j] = (f32x4){0.f, 0.f, 0.f, 0.f};

  int srow = 32 * w + (l >> 2);
  int scol = (l & 3) * 8;
  const u16* gA = A  + (size_t)(m0 + srow) * lda + scol;
  const u16* gB = Wb + (size_t)(n0 + srow) * K   + scol;
  u16* ldsA = As + (32 * w) * 32;
  u16* ldsB = Bs + (32 * w) * 32;

  int fr = l & 15;
  int kc = (l >> 4) * 8;
  const u16* rA = As + (size_t)(wr * 64 + fr) * 32 + kc;
  const u16* rB = Bs + (size_t)(wc * 64 + fr) * 32 + kc;

  for (int k0 = 0; k0 < K; k0 += 32) {
    gload16(gA + k0, ldsA);
    gload16(gA + (size_t)16 * lda + k0, ldsA + 16 * 32);
    gload16(gB + k0, ldsB);
    gload16(gB + (size_t)16 * K + k0, ldsB + 16 * 32);
    __syncthreads();
    bf16x8 a[4], b[4];
    #pragma unroll
    for (int i = 0; i < 4; ++i) a[i] = *(const bf16x8*)(rA + i * 16 * 32);
    #pragma unroll
    for (int j = 0; j < 4; ++j) b[j] = *(const bf16x8*)(rB + j * 16 * 32);
    #pragma unroll
    for (int i = 0; i < 4; ++i)
      #pragma unroll
      for (int j = 0; j < 4; ++j)
        acc[i][j] = __builtin_amdgcn_mfma_f32_16x16x32_bf16(a[i], b[j], acc[i][j], 0, 0, 0);
    __syncthreads();
  }

  int crow = (l >> 4) * 4;
  int ccol = l & 15;
  #pragma unroll
  for (int j = 0; j < 4; ++j) {
    int col = n0 + wc * 64 + j * 16 + ccol;
    int colr = col;
    if (REMAP) {
      int h = col / 192, r3 = col % 192;
      colr = (r3 / 64) * 2560 + h * 64 + (r3 & 63);
    }
    float bv = (EPI == 2) ? bias[col] : 0.f;
    #pragma unroll
    for (int i = 0; i < 4; ++i) {
      #pragma unroll
      for (int q = 0; q < 4; ++q) {
        int row = m0 + wr * 64 + i * 16 + crow + q;
        float v = acc[i][j][q];
        if constexpr (EPI == 1) v = 1.f / (1.f + expf(-v));
        if constexpr (EPI == 2) v = 1.f / (1.f + expf(v + bv));
        size_t idx = (size_t)row * ldc + colr;
        if constexpr (EPI == 5) v *= bf2f(C1[idx]);
        C1[idx] = f2bf(v);
      }
    }
  }
}

// ===============================================================
// Chunked parallel scan.
// Layout (phases 1,3): block = (bh, c), 128 threads = 2 waves.
//   wave wv in {0,1}; lane = sg*8+dd, sg=s-block (8 s), dd -> d0=wv*32+dd*4.
//   Thread owns st[8][4] = state[s0..s0+8)[d0..d0+4).
// Phase 1: local scan (zero init) -> y_local, S_c (fp32), P_c = prod(w).
// Phase 2: sequential combine over chunks -> st_in per chunk (overwrites S),
//          fstate output.
// Phase 3: y += C . (cumprod_w * st_in)   (RMW on y rows).
// Prefetch overruns (<=4 rows past chunk) stay inside d_ws, never consumed.
// ===============================================================
__global__ __launch_bounds__(128) void scan_local_kernel(
    const u16* __restrict__ wdec, const u16* __restrict__ proj,
    const u16* __restrict__ kvb, u16* __restrict__ yout,
    float* __restrict__ Sbuf, float* __restrict__ Pbuf) {
  int bx = blockIdx.x;
  int bh = bx / NC, c = bx % NC;
  int b = bh / NH, h = bh % NH;
  int wv = threadIdx.x >> 6;
  int lane = threadIdx.x & 63;
  int sg = lane >> 3, dd = lane & 7;
  int s0 = sg * 8;
  int d0 = wv * 32 + dd * 4;
  int l0 = c * CH;

  const u16* fw = wdec + ((size_t)(b * LL + l0)) * DIM + h * 64 + s0;
  const u16* fB = proj + ((size_t)(b * LL + l0)) * NPROJ + 2560 + h * 64 + s0;
  const u16* fC = fB + 2560;
  const u16* fk = kvb + ((size_t)(b * LL + l0)) * DIM + h * 64 + d0;
  u16* py = yout + ((size_t)(b * LL + l0)) * NPROJ + h * 64 + d0;

  float st[8][4];
  float pc[8];
  #pragma unroll
  for (int i = 0; i < 8; ++i) {
    pc[i] = 1.f;
    #pragma unroll
    for (int j = 0; j < 4; ++j) st[i][j] = 0.f;
  }

#define P1_DECL(n) uint4 wS##n, BS##n, CS##n; uint2 kS##n
#define P1_LOAD(n) do { \
    wS##n = *(const uint4*)fw; BS##n = *(const uint4*)fB; \
    CS##n = *(const uint4*)fC; kS##n = *(const uint2*)fk; \
    fw += DIM; fB += NPROJ; fC += NPROJ; fk += DIM; } while (0)
#define P1_PROC(n) do { \
    float wv8[8], Bv[8], Cv[8], kv4[4], pr[4]; \
    wv8[0]=bflo(wS##n.x); wv8[1]=bfhi(wS##n.x); wv8[2]=bflo(wS##n.y); wv8[3]=bfhi(wS##n.y); \
    wv8[4]=bflo(wS##n.z); wv8[5]=bfhi(wS##n.z); wv8[6]=bflo(wS##n.w); wv8[7]=bfhi(wS##n.w); \
    Bv[0]=bflo(BS##n.x); Bv[1]=bfhi(BS##n.x); Bv[2]=bflo(BS##n.y); Bv[3]=bfhi(BS##n.y); \
    Bv[4]=bflo(BS##n.z); Bv[5]=bfhi(BS##n.z); Bv[6]=bflo(BS##n.w); Bv[7]=bfhi(BS##n.w); \
    Cv[0]=bflo(CS##n.x); Cv[1]=bfhi(CS##n.x); Cv[2]=bflo(CS##n.y); Cv[3]=bfhi(CS##n.y); \
    Cv[4]=bflo(CS##n.z); Cv[5]=bfhi(CS##n.z); Cv[6]=bflo(CS##n.w); Cv[7]=bfhi(CS##n.w); \
    kv4[0]=bflo(kS##n.x); kv4[1]=bfhi(kS##n.x); kv4[2]=bflo(kS##n.y); kv4[3]=bfhi(kS##n.y); \
    pr[0]=0.f; pr[1]=0.f; pr[2]=0.f; pr[3]=0.f; \
    _Pragma("unroll") \
    for (int i = 0; i < 8; ++i) { \
      pc[i] *= wv8[i]; \
      _Pragma("unroll") \
      for (int j = 0; j < 4; ++j) { \
        st[i][j] = fmaf(wv8[i], st[i][j], Bv[i] * kv4[j]); \
        pr[j] = fmaf(st[i][j], Cv[i], pr[j]); } } \
    _Pragma("unroll") \
    for (int j = 0; j < 4; ++j) { \
      pr[j] += __shfl_xor(pr[j], 8, 64); \
      pr[j] += __shfl_xor(pr[j], 16, 64); \
      pr[j] += __shfl_xor(pr[j], 32, 64); } \
    if (lane < 8) { \
      uint2 ov; \
      ov.x = (unsigned)f2bf(pr[0]) | ((unsigned)f2bf(pr[1]) << 16); \
      ov.y = (unsigned)f2bf(pr[2]) | ((unsigned)f2bf(pr[3]) << 16); \
      *(uint2*)py = ov; } \
    py += NPROJ; } while (0)

  P1_DECL(0); P1_DECL(1); P1_DECL(2); P1_DECL(3);
  P1_LOAD(0); P1_LOAD(1); P1_LOAD(2); P1_LOAD(3);
  for (int l = 0; l < CH; l += 4) {
    P1_PROC(0); P1_LOAD(0);
    P1_PROC(1); P1_LOAD(1);
    P1_PROC(2); P1_LOAD(2);
    P1_PROC(3); P1_LOAD(3);
  }
#undef P1_DECL
#undef P1_LOAD
#undef P1_PROC

  // store chunk-local final state (fp32) and decay product
  float* Sp = Sbuf + (((size_t)c * BH + bh) * 64 + s0) * 64 + d0;
  #pragma unroll
  for (int i = 0; i < 8; ++i) {
    float4 v; v.x = st[i][0]; v.y = st[i][1]; v.z = st[i][2]; v.w = st[i][3];
    *(float4*)(Sp + (size_t)i * 64) = v;
  }
  if (wv == 0 && dd == 0) {
    #pragma unroll
    for (int i = 0; i < 8; ++i)
      Pbuf[((size_t)c * BH + bh) * 64 + s0 + i] = pc[i];
  }
}

// ---------------------------------------------------------------
__global__ __launch_bounds__(256) void scan_combine_kernel(
    float* __restrict__ Sbuf, const float* __restrict__ Pbuf,
    float* __restrict__ fstate) {
  int bh = blockIdx.x;
  int t = threadIdx.x;
  int s = t >> 2, j0 = (t & 3) * 16;
  float stin[16];
  #pragma unroll
  for (int k = 0; k < 16; ++k) stin[k] = 0.f;
  for (int c = 0; c < NC; ++c) {
    float* Sp = Sbuf + (((size_t)c * BH + bh) * 64 + s) * 64 + j0;
    float Pc = Pbuf[((size_t)c * BH + bh) * 64 + s];
    #pragma unroll
    for (int q = 0; q < 4; ++q) {
      float4 a = *(const float4*)(Sp + q * 4);
      float4 cur;
      cur.x = stin[q*4+0]; cur.y = stin[q*4+1];
      cur.z = stin[q*4+2]; cur.w = stin[q*4+3];
      *(float4*)(Sp + q * 4) = cur;           // S slot now holds st_in for chunk c
      stin[q*4+0] = a.x + Pc * stin[q*4+0];
      stin[q*4+1] = a.y + Pc * stin[q*4+1];
      stin[q*4+2] = a.z + Pc * stin[q*4+2];
      stin[q*4+3] = a.w + Pc * stin[q*4+3];
    }
  }
  float* fp = fstate + ((size_t)bh * 64 + s) * 64 + j0;
  #pragma unroll
  for (int q = 0; q < 4; ++q) {
    float4 v;
    v.x = stin[q*4+0]; v.y = stin[q*4+1];
    v.z = stin[q*4+2]; v.w = stin[q*4+3];
    *(float4*)(fp + q * 4) = v;
  }
}

// ---------------------------------------------------------------
__global__ __launch_bounds__(128) void scan_correct_kernel(
    const u16* __restrict__ wdec, const u16* __restrict__ proj,
    const float* __restrict__ Sbuf, u16* __restrict__ yio) {
  int bx = blockIdx.x;
  int bh = bx / NC, c = bx % NC;
  int b = bh / NH, h = bh % NH;
  int wv = threadIdx.x >> 6;
  int lane = threadIdx.x & 63;
  int sg = lane >> 3, dd = lane & 7;
  int s0 = sg * 8;
  int d0 = wv * 32 + dd * 4;
  int l0 = c * CH;

  // load st_in (fp32)
  const float* Sp = Sbuf + (((size_t)c * BH + bh) * 64 + s0) * 64 + d0;
  float stin[8][4];
  #pragma unroll
  for (int i = 0; i < 8; ++i) {
    float4 v = *(const float4*)(Sp + (size_t)i * 64);
    stin[i][0] = v.x; stin[i][1] = v.y; stin[i][2] = v.z; stin[i][3] = v.w;
  }

  const u16* fw = wdec + ((size_t)(b * LL + l0)) * DIM + h * 64 + s0;
  const u16* fC = proj + ((size_t)(b * LL + l0)) * NPROJ + 5120 + h * 64 + s0;
  const u16* fy = yio  + ((size_t)(b * LL + l0)) * NPROJ + h * 64 + d0;
  u16* py = yio + ((size_t)(b * LL + l0)) * NPROJ + h * 64 + d0;

  float pc[8];
  #pragma unroll
  for (int i = 0; i < 8; ++i) pc[i] = 1.f;

#define P3_DECL(n) uint4 wT##n, CT##n; uint2 yT##n
#define P3_LOAD(n) do { \
    wT##n = *(const uint4*)fw; CT##n = *(const uint4*)fC; \
    yT##n = *(const uint2*)fy; \
    fw += DIM; fC += NPROJ; fy += NPROJ; } while (0)
#define P3_PROC(n) do { \
    float wv8[8], Cv[8], ac[8], pr[4]; \
    wv8[0]=bflo(wT##n.x); wv8[1]=bfhi(wT##n.x); wv8[2]=bflo(wT##n.y); wv8[3]=bfhi(wT##n.y); \
    wv8[4]=bflo(wT##n.z); wv8[5]=bfhi(wT##n.z); wv8[6]=bflo(wT##n.w); wv8[7]=bfhi(wT##n.w); \
    Cv[0]=bflo(CT##n.x); Cv[1]=bfhi(CT##n.x); Cv[2]=bflo(CT##n.y); Cv[3]=bfhi(CT##n.y); \
    Cv[4]=bflo(CT##n.z); Cv[5]=bfhi(CT##n.z); Cv[6]=bflo(CT##n.w); Cv[7]=bfhi(CT##n.w); \
    pr[0]=0.f; pr[1]=0.f; pr[2]=0.f; pr[3]=0.f; \
    _Pragma("unroll") \
    for (int i = 0; i < 8; ++i) { \
      pc[i] *= wv8[i]; ac[i] = pc[i] * Cv[i]; \
      _Pragma("unroll") \
      for (int j = 0; j < 4; ++j) pr[j] = fmaf(ac[i], stin[i][j], pr[j]); } \
    _Pragma("unroll") \
    for (int j = 0; j < 4; ++j) { \
      pr[j] += __shfl_xor(pr[j], 8, 64); \
      pr[j] += __shfl_xor(pr[j], 16, 64); \
      pr[j] += __shfl_xor(pr[j], 32, 64); } \
    if (lane < 8) { \
      float y0 = bflo(yT##n.x) + pr[0]; \
      float y1 = bfhi(yT##n.x) + pr[1]; \
      float y2 = bflo(yT##n.y) + pr[2]; \
      float y3 = bfhi(yT##n.y) + pr[3]; \
      uint2 ov; \
      ov.x = (unsigned)f2bf(y0) | ((unsigned)f2bf(y1) << 16); \
      ov.y = (unsigned)f2bf(y2) | ((unsigned)f2bf(y3) << 16); \
      *(uint2*)py = ov; } \
    py += NPROJ; } while (0)

  P3_DECL(0); P3_DECL(1); P3_DECL(2); P3_DECL(3);
  P3_LOAD(0); P3_LOAD(1); P3_LOAD(2); P3_LOAD(3);
  for (int l = 0; l < CH; l += 4) {
    P3_PROC(0); P3_LOAD(0);
    P3_PROC(1); P3_LOAD(1);
    P3_PROC(2); P3_LOAD(2);
    P3_PROC(3); P3_LOAD(3);
  }
#undef P3_DECL
#undef P3_LOAD
#undef P3_PROC
}

// ---------------------------------------------------------------
// gate: out_inner = r * y * g   (y in proj dt-region cols 0..2560)
// ---------------------------------------------------------------
__global__ __launch_bounds__(320) void gate_kernel(
    const u16* __restrict__ proj, const u16* __restrict__ rb,
    const u16* __restrict__ gb, u16* __restrict__ outi) {
  int bl = blockIdx.x, t = threadIdx.x;
  uint4 yv = *(const uint4*)(proj + (size_t)bl * NPROJ + t * 8);
  uint4 rv = *(const uint4*)(rb + (size_t)bl * DIM + t * 8);
  uint4 gv = *(const uint4*)(gb + (size_t)bl * DIM + t * 8);
  unsigned yw[4] = {yv.x, yv.y, yv.z, yv.w};
  unsigned rw[4] = {rv.x, rv.y, rv.z, rv.w};
  unsigned gw[4] = {gv.x, gv.y, gv.z, gv.w};
  u16 res[8];
  #pragma unroll
  for (int i = 0; i < 4; ++i) {
    res[2*i]   = f2bf(bflo(yw[i]) * bflo(rw[i]) * bflo(gw[i]));
    res[2*i+1] = f2bf(bfhi(yw[i]) * bfhi(rw[i]) * bfhi(gw[i]));
  }
  uint4 ov;
  ov.x = (unsigned)res[0] | ((unsigned)res[1] << 16);
  ov.y = (unsigned)res[2] | ((unsigned)res[3] << 16);
  ov.z = (unsigned)res[4] | ((unsigned)res[5] << 16);
  ov.w = (unsigned)res[6] | ((unsigned)res[7] << 16);
  *(uint4*)(outi + (size_t)bl * DIM + t * 8) = ov;
}

// ---------------------------------------------------------------
extern "C" void kernel_launch(void* const* d_in, const int* in_sizes, int n_in,
                              void* d_out, int out_size, void* d_ws, size_t ws_size,
                              hipStream_t stream) {
  const float* x    = (const float*)d_in[0];
  const float* W_r  = (const float*)d_in[1];
  const float* W_k  = (const float*)d_in[2];
  const float* W_v  = (const float*)d_in[3];
  const float* W_g  = (const float*)d_in[4];
  const float* W_xp = (const float*)d_in[5];
  const float* W_dt = (const float*)d_in[6];
  const float* b_dt = (const float*)d_in[7];
  const float* cw   = (const float*)d_in[8];
  const float* ln1g = (const float*)d_in[9];
  const float* ln1b = (const float*)d_in[10];
  const float* ln2g = (const float*)d_in[11];
  const float* ln2b = (const float*)d_in[12];
  const float* W_o  = (const float*)d_in[13];

  float* out    = (float*)d_out;
  float* fstate = out + (size_t)MTOT * DIM;

  const size_t nBL = (size_t)MTOT * DIM;
  const size_t nPJ = (size_t)MTOT * NPROJ;
  const size_t nWX = (size_t)NPROJ * DIM;
  const size_t needed = (nBL * 5 + nPJ + nWX) * sizeof(u16);  // ~207 MB
  if (ws_size < needed) {
    fill_kernel<<<(out_size + 255) / 256, 256, 0, stream>>>(out, out_size, 1234.5f);
    return;
  }

  u16* wsp  = (u16*)d_ws;
  u16* x1   = wsp;
  u16* proj = x1 + nBL;
  u16* wdec = proj + nPJ;       // reused for y2 after recurrence
  u16* rb   = wdec + nBL;
  u16* gb   = rb + nBL;
  u16* kvb  = gb + nBL;         // k -> kv; out_inner after gate
  u16* wscr = kvb + nBL;        // weight scratch; scan S/P live here during scan
  float* Sbuf = (float*)wscr;                       // NC*BH*64*64 fp32 = 21 MB
  float* Pbuf = Sbuf + (size_t)NC * BH * 64 * 64;   // NC*BH*64 fp32 = 0.3 MB

  const int nDD4 = DIM * DIM / 4;

  // 1. conv + LN1 -> x1 (bf16)
  conv_ln1_kernel<<<MTOT, 256, 0, stream>>>(x, cw, ln1g, ln1b, x1);

  // 2. proj = x1 @ W_xproj^T  (REMAP columns to [dt|B|C])
  cvt_kernel<<<2048, 256, 0, stream>>>(W_xp, wscr, NPROJ * DIM / 4);
  gemm_mfma<0,true ><<<dim3(NPROJ/128, MTOT/128), 256, 0, stream>>>(x1, DIM, wscr, nullptr, proj, NPROJ, DIM);

  // 3. w = exp(-softplus(proj_dt @ W_dt^T + b_dt))
  cvt_kernel<<<2048, 256, 0, stream>>>(W_dt, wscr, nDD4);
  gemm_mfma<2,false><<<dim3(DIM/128, MTOT/128), 256, 0, stream>>>(proj, NPROJ, wscr, b_dt, wdec, DIM, DIM);

  // 4. r = sigmoid(x1 @ W_r^T)
  cvt_kernel<<<2048, 256, 0, stream>>>(W_r, wscr, nDD4);
  gemm_mfma<1,false><<<dim3(DIM/128, MTOT/128), 256, 0, stream>>>(x1, DIM, wscr, nullptr, rb, DIM, DIM);

  // 5. g = sigmoid(x1 @ W_g^T)
  cvt_kernel<<<2048, 256, 0, stream>>>(W_g, wscr, nDD4);
  gemm_mfma<1,false><<<dim3(DIM/128, MTOT/128), 256, 0, stream>>>(x1, DIM, wscr, nullptr, gb, DIM, DIM);

  // 6. k = x1 @ W_k^T
  cvt_kernel<<<2048, 256, 0, stream>>>(W_k, wscr, nDD4);
  gemm_mfma<0,false><<<dim3(DIM/128, MTOT/128), 256, 0, stream>>>(x1, DIM, wscr, nullptr, kvb, DIM, DIM);

  // 7. kv = k * (x1 @ W_v^T)
  cvt_kernel<<<2048, 256, 0, stream>>>(W_v, wscr, nDD4);
  gemm_mfma<5,false><<<dim3(DIM/128, MTOT/128), 256, 0, stream>>>(x1, DIM, wscr, nullptr, kvb, DIM, DIM);

  // 8. chunked scan: phase 1 (local), phase 2 (combine -> fstate), phase 3 (correct)
  scan_local_kernel<<<BH * NC, 128, 0, stream>>>(wdec, proj, kvb, proj, Sbuf, Pbuf);
  scan_combine_kernel<<<BH, 256, 0, stream>>>(Sbuf, Pbuf, fstate);
  scan_correct_kernel<<<BH * NC, 128, 0, stream>>>(wdec, proj, Sbuf, proj);

  // 9. out_inner = r * y * g  -> kvb (reuse)
  gate_kernel<<<MTOT, 320, 0, stream>>>(proj, rb, gb, kvb);

  // 10. y2 = out_inner @ W_out^T -> wdec (reuse)
  cvt_kernel<<<2048, 256, 0, stream>>>(W_o, wscr, nDD4);
  gemm_mfma<0,false><<<dim3(DIM/128, MTOT/128), 256, 0, stream>>>(kvb, DIM, wscr, nullptr, wdec, DIM, DIM);

  // 11. out = LN(x1 + y2) -> fp32
  ln2_kernel<<<MTOT, 256, 0, stream>>>(x1, wdec, ln2g, ln2b, out);
}

// Round 8
// 1077.038 us; speedup vs baseline: 8.0019x; 1.0078x over previous
//
#include <hip/hip_runtime.h>
#include <cstddef>
#include <cstdint>

#define DIM 2560
#define NH 40
#define HDD 64
#define SD 64
#define KC 4
#define BB 2
#define LL 2048
#define MTOT (BB*LL)      // 4096
#define NPROJ (NH*3*SD)   // 7680
#define NC 16             // scan chunks
#define CH (LL/NC)        // 128 steps per chunk
#define BH (BB*NH)        // 80

typedef unsigned short u16;
typedef __attribute__((ext_vector_type(8))) short bf16x8;
typedef __attribute__((ext_vector_type(4))) float f32x4;

__device__ inline float bf2f(u16 u) { return __uint_as_float(((unsigned)u) << 16); }
__device__ inline float bflo(unsigned u) { return __uint_as_float(u << 16); }
__device__ inline float bfhi(unsigned u) { return __uint_as_float(u & 0xffff0000u); }
__device__ inline u16 f2bf(float f) {
  unsigned x = __float_as_uint(f);
  unsigned r = (x + 0x7fffu + ((x >> 16) & 1u)) >> 16;   // RNE
  return (u16)r;
}

__device__ inline void gload16(const void* g, void* lds) {
  __builtin_amdgcn_global_load_lds(
      (const __attribute__((address_space(1))) void*)g,
      (__attribute__((address_space(3))) void*)(uint32_t)(size_t)lds,
      16, 0, 0);
}

// ---------------------------------------------------------------
__global__ __launch_bounds__(256) void cvt_kernel(
    const float* __restrict__ src, u16* __restrict__ dst, int n4) {
  int i = blockIdx.x * 256 + threadIdx.x;
  int stride = gridDim.x * 256;
  for (; i < n4; i += stride) {
    float4 v = *(const float4*)(src + (size_t)i * 4);
    ushort4 o;
    o.x = f2bf(v.x); o.y = f2bf(v.y); o.z = f2bf(v.z); o.w = f2bf(v.w);
    *(ushort4*)(dst + (size_t)i * 4) = o;
  }
}

// ---------------------------------------------------------------
__global__ __launch_bounds__(256) void fill_kernel(float* p, int n, float v) {
  int i = blockIdx.x * 256 + threadIdx.x;
  if (i < n) p[i] = v;
}

// ---------------------------------------------------------------
__device__ inline void block_reduce2(float& sum, float& sq, float* red) {
  #pragma unroll
  for (int off = 32; off; off >>= 1) {
    sum += __shfl_down(sum, off, 64);
    sq  += __shfl_down(sq,  off, 64);
  }
  int wid = threadIdx.x >> 6, lane = threadIdx.x & 63;
  if (lane == 0) { red[wid*2] = sum; red[wid*2+1] = sq; }
  __syncthreads();
  sum = red[0] + red[2] + red[4] + red[6];
  sq  = red[1] + red[3] + red[5] + red[7];
}

// ---------------------------------------------------------------
// conv (causal depthwise, K=4) + residual + LayerNorm1 -> bf16
// ---------------------------------------------------------------
__global__ __launch_bounds__(256) void conv_ln1_kernel(
    const float* __restrict__ x, const float* __restrict__ cw,
    const float* __restrict__ g1, const float* __restrict__ b1,
    u16* __restrict__ x1) {
  __shared__ float red[8];
  int bl = blockIdx.x;
  int l  = bl & (LL - 1);
  int t  = threadIdx.x;
  const float* xr = x + (size_t)bl * DIM;
  float vals[10];
  float sum = 0.f, sq = 0.f;
  #pragma unroll
  for (int i = 0; i < 10; ++i) {
    int d = t + 256 * i;
    float acc = xr[d];
    #pragma unroll
    for (int j = 0; j < KC; ++j) {
      int ll = l - (KC - 1) + j;
      if (ll >= 0) acc += x[(size_t)(bl - l + ll) * DIM + d] * cw[d * KC + j];
    }
    vals[i] = acc; sum += acc; sq += acc * acc;
  }
  block_reduce2(sum, sq, red);
  float mean = sum * (1.f / DIM);
  float var  = sq * (1.f / DIM) - mean * mean;
  float rstd = rsqrtf(var + 1e-5f);
  u16* orow = x1 + (size_t)bl * DIM;
  #pragma unroll
  for (int i = 0; i < 10; ++i) {
    int d = t + 256 * i;
    orow[d] = f2bf((vals[i] - mean) * rstd * g1[d] + b1[d]);
  }
}

// ---------------------------------------------------------------
// LN2: out = LN(x1 + y2), bf16 inputs -> fp32 out
// ---------------------------------------------------------------
__global__ __launch_bounds__(256) void ln2_kernel(
    const u16* __restrict__ x1, const u16* __restrict__ y2,
    const float* __restrict__ g2, const float* __restrict__ b2,
    float* __restrict__ out) {
  __shared__ float red[8];
  int bl = blockIdx.x;
  int t  = threadIdx.x;
  const u16* ar = x1 + (size_t)bl * DIM;
  const u16* br = y2 + (size_t)bl * DIM;
  float vals[10];
  float sum = 0.f, sq = 0.f;
  #pragma unroll
  for (int i = 0; i < 10; ++i) {
    int d = t + 256 * i;
    float v = bf2f(ar[d]) + bf2f(br[d]);
    vals[i] = v; sum += v; sq += v * v;
  }
  block_reduce2(sum, sq, red);
  float mean = sum * (1.f / DIM);
  float var  = sq * (1.f / DIM) - mean * mean;
  float rstd = rsqrtf(var + 1e-5f);
  float* orow = out + (size_t)bl * DIM;
  #pragma unroll
  for (int i = 0; i < 10; ++i) {
    int d = t + 256 * i;
    orow[d] = (vals[i] - mean) * rstd * g2[d] + b2[d];
  }
}

// ---------------------------------------------------------------
// MFMA bf16 GEMM, BK=64: C[M,N] = epi(A[M,K] @ W[N,K]^T)
// 128x128 tile, 256 threads (4 waves, 2x2), 4x4 frags/wave.
// LDS: two [128][32] K-subtiles per operand (row stride 64B).
// 40 K-iters at K=2560 (half the barriers of BK=32).
// XCD-bijective block swizzle (grids here are %8==0).
// EPI: 0 plain | 1 sigmoid | 2 decay sigmoid(-(v+bias)) | 5 C *= acc
// ---------------------------------------------------------------
template<int EPI, bool REMAP>
__global__ __launch_bounds__(256) void gemm_mfma(
    const u16* __restrict__ A, int lda,
    const u16* __restrict__ Wb,
    const float* __restrict__ bias,
    u16* __restrict__ C1, int ldc,
    int K) {
  __shared__ u16 As[2 * 128 * 32];
  __shared__ u16 Bs[2 * 128 * 32];
  int t = threadIdx.x;
  int w = t >> 6, l = t & 63;
  int wr = w >> 1, wc = w & 1;

  // T1: XCD-aware bijective swizzle of the linear workgroup id
  int nx  = gridDim.x;
  int nwg = nx * gridDim.y;
  int wg  = blockIdx.y * nx + blockIdx.x;
  int cpx = nwg >> 3;
  int swz = (wg & 7) * cpx + (wg >> 3);
  int m0 = (swz / nx) * 128;
  int n0 = (swz % nx) * 128;

  f32x4 acc[4][4];
  #pragma unroll
  for (int i = 0; i < 4; ++i)
    #pragma unroll
    for (int j = 0; j < 4; ++j)
      acc[i][j] = (f32x4){0.f, 0.f, 0.f, 0.f};

  // staging: wave w owns rows 32w..32w+31; per call 16 rows x 32 cols
  int srow = l >> 2;            // 0..15 within a 16-row call block
  int scol = (l & 3) * 8;       // 0,8,16,24 (u16)
  const u16* gA = A  + (size_t)(m0 + 32 * w + srow) * lda + scol;
  const u16* gB = Wb + (size_t)(n0 + 32 * w + srow) * K   + scol;
  u16* ldsA = As + (32 * w) * 32;   // wave-uniform base (ks=0, rr=0)
  u16* ldsB = Bs + (32 * w) * 32;

  // fragment read addresses
  int fr = l & 15;
  int kc = (l >> 4) * 8;
  const u16* rA = As + (size_t)(wr * 64 + fr) * 32 + kc;
  const u16* rB = Bs + (size_t)(wc * 64 + fr) * 32 + kc;

  for (int k0 = 0; k0 < K; k0 += 64) {
    #pragma unroll
    for (int q = 0; q < 4; ++q) {
      const int ks = q >> 1, rr = q & 1;
      gload16(gA + (size_t)(rr * 16) * lda + k0 + ks * 32,
              ldsA + ks * 4096 + rr * 512);
      gload16(gB + (size_t)(rr * 16) * K + k0 + ks * 32,
              ldsB + ks * 4096 + rr * 512);
    }
    __syncthreads();
    bf16x8 a[4][2], b[4][2];
    #pragma unroll
    for (int i = 0; i < 4; ++i) {
      a[i][0] = *(const bf16x8*)(rA + i * 512);
      a[i][1] = *(const bf16x8*)(rA + 4096 + i * 512);
      b[i][0] = *(const bf16x8*)(rB + i * 512);
      b[i][1] = *(const bf16x8*)(rB + 4096 + i * 512);
    }
    #pragma unroll
    for (int ks = 0; ks < 2; ++ks)
      #pragma unroll
      for (int i = 0; i < 4; ++i)
        #pragma unroll
        for (int j = 0; j < 4; ++j)
          acc[i][j] = __builtin_amdgcn_mfma_f32_16x16x32_bf16(a[i][ks], b[j][ks], acc[i][j], 0, 0, 0);
    __syncthreads();
  }

  // epilogue: C/D mapping col = lane&15, row = (lane>>4)*4 + q [m89]
  int crow = (l >> 4) * 4;
  int ccol = l & 15;
  #pragma unroll
  for (int j = 0; j < 4; ++j) {
    int col = n0 + wc * 64 + j * 16 + ccol;
    int colr = col;
    if (REMAP) {
      int h = col / 192, r3 = col % 192;
      colr = (r3 / 64) * 2560 + h * 64 + (r3 & 63);
    }
    float bv = (EPI == 2) ? bias[col] : 0.f;
    #pragma unroll
    for (int i = 0; i < 4; ++i) {
      #pragma unroll
      for (int q = 0; q < 4; ++q) {
        int row = m0 + wr * 64 + i * 16 + crow + q;
        float v = acc[i][j][q];
        if constexpr (EPI == 1) v = 1.f / (1.f + expf(-v));
        if constexpr (EPI == 2) v = 1.f / (1.f + expf(v + bv));
        size_t idx = (size_t)row * ldc + colr;
        if constexpr (EPI == 5) v *= bf2f(C1[idx]);
        C1[idx] = f2bf(v);
      }
    }
  }
}

// ===============================================================
// Chunked parallel scan (same structure as round 7).
// Phase 3 now also applies the r*g gate so out_inner lands in the
// proj y-region directly (gate kernel eliminated).
// ===============================================================
__global__ __launch_bounds__(128) void scan_local_kernel(
    const u16* __restrict__ wdec, const u16* __restrict__ proj,
    const u16* __restrict__ kvb, u16* __restrict__ yout,
    float* __restrict__ Sbuf, float* __restrict__ Pbuf) {
  int bx = blockIdx.x;
  int bh = bx / NC, c = bx % NC;
  int b = bh / NH, h = bh % NH;
  int wv = threadIdx.x >> 6;
  int lane = threadIdx.x & 63;
  int sg = lane >> 3, dd = lane & 7;
  int s0 = sg * 8;
  int d0 = wv * 32 + dd * 4;
  int l0 = c * CH;

  const u16* fw = wdec + ((size_t)(b * LL + l0)) * DIM + h * 64 + s0;
  const u16* fB = proj + ((size_t)(b * LL + l0)) * NPROJ + 2560 + h * 64 + s0;
  const u16* fC = fB + 2560;
  const u16* fk = kvb + ((size_t)(b * LL + l0)) * DIM + h * 64 + d0;
  u16* py = yout + ((size_t)(b * LL + l0)) * NPROJ + h * 64 + d0;

  float st[8][4];
  float pc[8];
  #pragma unroll
  for (int i = 0; i < 8; ++i) {
    pc[i] = 1.f;
    #pragma unroll
    for (int j = 0; j < 4; ++j) st[i][j] = 0.f;
  }

#define P1_DECL(n) uint4 wS##n, BS##n, CS##n; uint2 kS##n
#define P1_LOAD(n) do { \
    wS##n = *(const uint4*)fw; BS##n = *(const uint4*)fB; \
    CS##n = *(const uint4*)fC; kS##n = *(const uint2*)fk; \
    fw += DIM; fB += NPROJ; fC += NPROJ; fk += DIM; } while (0)
#define P1_PROC(n) do { \
    float wv8[8], Bv[8], Cv[8], kv4[4], pr[4]; \
    wv8[0]=bflo(wS##n.x); wv8[1]=bfhi(wS##n.x); wv8[2]=bflo(wS##n.y); wv8[3]=bfhi(wS##n.y); \
    wv8[4]=bflo(wS##n.z); wv8[5]=bfhi(wS##n.z); wv8[6]=bflo(wS##n.w); wv8[7]=bfhi(wS##n.w); \
    Bv[0]=bflo(BS##n.x); Bv[1]=bfhi(BS##n.x); Bv[2]=bflo(BS##n.y); Bv[3]=bfhi(BS##n.y); \
    Bv[4]=bflo(BS##n.z); Bv[5]=bfhi(BS##n.z); Bv[6]=bflo(BS##n.w); Bv[7]=bfhi(BS##n.w); \
    Cv[0]=bflo(CS##n.x); Cv[1]=bfhi(CS##n.x); Cv[2]=bflo(CS##n.y); Cv[3]=bfhi(CS##n.y); \
    Cv[4]=bflo(CS##n.z); Cv[5]=bfhi(CS##n.z); Cv[6]=bflo(CS##n.w); Cv[7]=bfhi(CS##n.w); \
    kv4[0]=bflo(kS##n.x); kv4[1]=bfhi(kS##n.x); kv4[2]=bflo(kS##n.y); kv4[3]=bfhi(kS##n.y); \
    pr[0]=0.f; pr[1]=0.f; pr[2]=0.f; pr[3]=0.f; \
    _Pragma("unroll") \
    for (int i = 0; i < 8; ++i) { \
      pc[i] *= wv8[i]; \
      _Pragma("unroll") \
      for (int j = 0; j < 4; ++j) { \
        st[i][j] = fmaf(wv8[i], st[i][j], Bv[i] * kv4[j]); \
        pr[j] = fmaf(st[i][j], Cv[i], pr[j]); } } \
    _Pragma("unroll") \
    for (int j = 0; j < 4; ++j) { \
      pr[j] += __shfl_xor(pr[j], 8, 64); \
      pr[j] += __shfl_xor(pr[j], 16, 64); \
      pr[j] += __shfl_xor(pr[j], 32, 64); } \
    if (lane < 8) { \
      uint2 ov; \
      ov.x = (unsigned)f2bf(pr[0]) | ((unsigned)f2bf(pr[1]) << 16); \
      ov.y = (unsigned)f2bf(pr[2]) | ((unsigned)f2bf(pr[3]) << 16); \
      *(uint2*)py = ov; } \
    py += NPROJ; } while (0)

  P1_DECL(0); P1_DECL(1); P1_DECL(2); P1_DECL(3);
  P1_LOAD(0); P1_LOAD(1); P1_LOAD(2); P1_LOAD(3);
  for (int l = 0; l < CH; l += 4) {
    P1_PROC(0); P1_LOAD(0);
    P1_PROC(1); P1_LOAD(1);
    P1_PROC(2); P1_LOAD(2);
    P1_PROC(3); P1_LOAD(3);
  }
#undef P1_DECL
#undef P1_LOAD
#undef P1_PROC

  float* Sp = Sbuf + (((size_t)c * BH + bh) * 64 + s0) * 64 + d0;
  #pragma unroll
  for (int i = 0; i < 8; ++i) {
    float4 v; v.x = st[i][0]; v.y = st[i][1]; v.z = st[i][2]; v.w = st[i][3];
    *(float4*)(Sp + (size_t)i * 64) = v;
  }
  if (wv == 0 && dd == 0) {
    #pragma unroll
    for (int i = 0; i < 8; ++i)
      Pbuf[((size_t)c * BH + bh) * 64 + s0 + i] = pc[i];
  }
}

// ---------------------------------------------------------------
__global__ __launch_bounds__(256) void scan_combine_kernel(
    float* __restrict__ Sbuf, const float* __restrict__ Pbuf,
    float* __restrict__ fstate) {
  int bh = blockIdx.x;
  int t = threadIdx.x;
  int s = t >> 2, j0 = (t & 3) * 16;
  float stin[16];
  #pragma unroll
  for (int k = 0; k < 16; ++k) stin[k] = 0.f;
  for (int c = 0; c < NC; ++c) {
    float* Sp = Sbuf + (((size_t)c * BH + bh) * 64 + s) * 64 + j0;
    float Pc = Pbuf[((size_t)c * BH + bh) * 64 + s];
    #pragma unroll
    for (int q = 0; q < 4; ++q) {
      float4 a = *(const float4*)(Sp + q * 4);
      float4 cur;
      cur.x = stin[q*4+0]; cur.y = stin[q*4+1];
      cur.z = stin[q*4+2]; cur.w = stin[q*4+3];
      *(float4*)(Sp + q * 4) = cur;           // S slot now holds st_in for chunk c
      stin[q*4+0] = a.x + Pc * stin[q*4+0];
      stin[q*4+1] = a.y + Pc * stin[q*4+1];
      stin[q*4+2] = a.z + Pc * stin[q*4+2];
      stin[q*4+3] = a.w + Pc * stin[q*4+3];
    }
  }
  float* fp = fstate + ((size_t)bh * 64 + s) * 64 + j0;
  #pragma unroll
  for (int q = 0; q < 4; ++q) {
    float4 v;
    v.x = stin[q*4+0]; v.y = stin[q*4+1];
    v.z = stin[q*4+2]; v.w = stin[q*4+3];
    *(float4*)(fp + q * 4) = v;
  }
}

// ---------------------------------------------------------------
// Phase 3 + fused gate: y_final = r * (y_local + C.(cumw*st_in)) * g
// ---------------------------------------------------------------
__global__ __launch_bounds__(128) void scan_correct_kernel(
    const u16* __restrict__ wdec, const u16* __restrict__ proj,
    const u16* __restrict__ rb, const u16* __restrict__ gb,
    const float* __restrict__ Sbuf, u16* __restrict__ yio) {
  int bx = blockIdx.x;
  int bh = bx / NC, c = bx % NC;
  int b = bh / NH, h = bh % NH;
  int wv = threadIdx.x >> 6;
  int lane = threadIdx.x & 63;
  int sg = lane >> 3, dd = lane & 7;
  int s0 = sg * 8;
  int d0 = wv * 32 + dd * 4;
  int l0 = c * CH;

  const float* Sp = Sbuf + (((size_t)c * BH + bh) * 64 + s0) * 64 + d0;
  float stin[8][4];
  #pragma unroll
  for (int i = 0; i < 8; ++i) {
    float4 v = *(const float4*)(Sp + (size_t)i * 64);
    stin[i][0] = v.x; stin[i][1] = v.y; stin[i][2] = v.z; stin[i][3] = v.w;
  }

  const u16* fw = wdec + ((size_t)(b * LL + l0)) * DIM + h * 64 + s0;
  const u16* fC = proj + ((size_t)(b * LL + l0)) * NPROJ + 5120 + h * 64 + s0;
  const u16* fy = yio  + ((size_t)(b * LL + l0)) * NPROJ + h * 64 + d0;
  const u16* fr2 = rb + ((size_t)(b * LL + l0)) * DIM + h * 64 + d0;
  const u16* fg2 = gb + ((size_t)(b * LL + l0)) * DIM + h * 64 + d0;
  u16* py = yio + ((size_t)(b * LL + l0)) * NPROJ + h * 64 + d0;

  float pc[8];
  #pragma unroll
  for (int i = 0; i < 8; ++i) pc[i] = 1.f;

#define P3_DECL(n) uint4 wT##n, CT##n; uint2 yT##n, rT##n, gT##n
#define P3_LOAD(n) do { \
    wT##n = *(const uint4*)fw; CT##n = *(const uint4*)fC; \
    yT##n = *(const uint2*)fy; rT##n = *(const uint2*)fr2; gT##n = *(const uint2*)fg2; \
    fw += DIM; fC += NPROJ; fy += NPROJ; fr2 += DIM; fg2 += DIM; } while (0)
#define P3_PROC(n) do { \
    float wv8[8], Cv[8], ac[8], pr[4]; \
    wv8[0]=bflo(wT##n.x); wv8[1]=bfhi(wT##n.x); wv8[2]=bflo(wT##n.y); wv8[3]=bfhi(wT##n.y); \
    wv8[4]=bflo(wT##n.z); wv8[5]=bfhi(wT##n.z); wv8[6]=bflo(wT##n.w); wv8[7]=bfhi(wT##n.w); \
    Cv[0]=bflo(CT##n.x); Cv[1]=bfhi(CT##n.x); Cv[2]=bflo(CT##n.y); Cv[3]=bfhi(CT##n.y); \
    Cv[4]=bflo(CT##n.z); Cv[5]=bfhi(CT##n.z); Cv[6]=bflo(CT##n.w); Cv[7]=bfhi(CT##n.w); \
    pr[0]=0.f; pr[1]=0.f; pr[2]=0.f; pr[3]=0.f; \
    _Pragma("unroll") \
    for (int i = 0; i < 8; ++i) { \
      pc[i] *= wv8[i]; ac[i] = pc[i] * Cv[i]; \
      _Pragma("unroll") \
      for (int j = 0; j < 4; ++j) pr[j] = fmaf(ac[i], stin[i][j], pr[j]); } \
    _Pragma("unroll") \
    for (int j = 0; j < 4; ++j) { \
      pr[j] += __shfl_xor(pr[j], 8, 64); \
      pr[j] += __shfl_xor(pr[j], 16, 64); \
      pr[j] += __shfl_xor(pr[j], 32, 64); } \
    if (lane < 8) { \
      float y0 = (bflo(yT##n.x) + pr[0]) * bflo(rT##n.x) * bflo(gT##n.x); \
      float y1 = (bfhi(yT##n.x) + pr[1]) * bfhi(rT##n.x) * bfhi(gT##n.x); \
      float y2 = (bflo(yT##n.y) + pr[2]) * bflo(rT##n.y) * bflo(gT##n.y); \
      float y3 = (bfhi(yT##n.y) + pr[3]) * bfhi(rT##n.y) * bfhi(gT##n.y); \
      uint2 ov; \
      ov.x = (unsigned)f2bf(y0) | ((unsigned)f2bf(y1) << 16); \
      ov.y = (unsigned)f2bf(y2) | ((unsigned)f2bf(y3) << 16); \
      *(uint2*)py = ov; } \
    py += NPROJ; } while (0)

  P3_DECL(0); P3_DECL(1); P3_DECL(2); P3_DECL(3);
  P3_LOAD(0); P3_LOAD(1); P3_LOAD(2); P3_LOAD(3);
  for (int l = 0; l < CH; l += 4) {
    P3_PROC(0); P3_LOAD(0);
    P3_PROC(1); P3_LOAD(1);
    P3_PROC(2); P3_LOAD(2);
    P3_PROC(3); P3_LOAD(3);
  }
#undef P3_DECL
#undef P3_LOAD
#undef P3_PROC
}

// ---------------------------------------------------------------
extern "C" void kernel_launch(void* const* d_in, const int* in_sizes, int n_in,
                              void* d_out, int out_size, void* d_ws, size_t ws_size,
                              hipStream_t stream) {
  const float* x    = (const float*)d_in[0];
  const float* W_r  = (const float*)d_in[1];
  const float* W_k  = (const float*)d_in[2];
  const float* W_v  = (const float*)d_in[3];
  const float* W_g  = (const float*)d_in[4];
  const float* W_xp = (const float*)d_in[5];
  const float* W_dt = (const float*)d_in[6];
  const float* b_dt = (const float*)d_in[7];
  const float* cw   = (const float*)d_in[8];
  const float* ln1g = (const float*)d_in[9];
  const float* ln1b = (const float*)d_in[10];
  const float* ln2g = (const float*)d_in[11];
  const float* ln2b = (const float*)d_in[12];
  const float* W_o  = (const float*)d_in[13];

  float* out    = (float*)d_out;
  float* fstate = out + (size_t)MTOT * DIM;

  const size_t nBL = (size_t)MTOT * DIM;
  const size_t nPJ = (size_t)MTOT * NPROJ;
  const size_t nWX = (size_t)NPROJ * DIM;
  const size_t needed = (nBL * 5 + nPJ + nWX) * sizeof(u16);  // ~207 MB
  if (ws_size < needed) {
    fill_kernel<<<(out_size + 255) / 256, 256, 0, stream>>>(out, out_size, 1234.5f);
    return;
  }

  u16* wsp  = (u16*)d_ws;
  u16* x1   = wsp;
  u16* proj = x1 + nBL;
  u16* wdec = proj + nPJ;       // reused for y2 after recurrence
  u16* rb   = wdec + nBL;
  u16* gb   = rb + nBL;
  u16* kvb  = gb + nBL;         // k -> kv
  u16* wscr = kvb + nBL;        // weight scratch; scan S/P live here during scan
  float* Sbuf = (float*)wscr;                       // NC*BH*64*64 fp32 = 21 MB
  float* Pbuf = Sbuf + (size_t)NC * BH * 64 * 64;   // NC*BH*64 fp32 = 0.3 MB

  const int nDD4 = DIM * DIM / 4;

  // 1. conv + LN1 -> x1 (bf16)
  conv_ln1_kernel<<<MTOT, 256, 0, stream>>>(x, cw, ln1g, ln1b, x1);

  // 2. proj = x1 @ W_xproj^T  (REMAP columns to [dt|B|C])
  cvt_kernel<<<2048, 256, 0, stream>>>(W_xp, wscr, NPROJ * DIM / 4);
  gemm_mfma<0,true ><<<dim3(NPROJ/128, MTOT/128), 256, 0, stream>>>(x1, DIM, wscr, nullptr, proj, NPROJ, DIM);

  // 3. w = exp(-softplus(proj_dt @ W_dt^T + b_dt))
  cvt_kernel<<<2048, 256, 0, stream>>>(W_dt, wscr, nDD4);
  gemm_mfma<2,false><<<dim3(DIM/128, MTOT/128), 256, 0, stream>>>(proj, NPROJ, wscr, b_dt, wdec, DIM, DIM);

  // 4. r = sigmoid(x1 @ W_r^T)
  cvt_kernel<<<2048, 256, 0, stream>>>(W_r, wscr, nDD4);
  gemm_mfma<1,false><<<dim3(DIM/128, MTOT/128), 256, 0, stream>>>(x1, DIM, wscr, nullptr, rb, DIM, DIM);

  // 5. g = sigmoid(x1 @ W_g^T)
  cvt_kernel<<<2048, 256, 0, stream>>>(W_g, wscr, nDD4);
  gemm_mfma<1,false><<<dim3(DIM/128, MTOT/128), 256, 0, stream>>>(x1, DIM, wscr, nullptr, gb, DIM, DIM);

  // 6. k = x1 @ W_k^T
  cvt_kernel<<<2048, 256, 0, stream>>>(W_k, wscr, nDD4);
  gemm_mfma<0,false><<<dim3(DIM/128, MTOT/128), 256, 0, stream>>>(x1, DIM, wscr, nullptr, kvb, DIM, DIM);

  // 7. kv = k * (x1 @ W_v^T)
  cvt_kernel<<<2048, 256, 0, stream>>>(W_v, wscr, nDD4);
  gemm_mfma<5,false><<<dim3(DIM/128, MTOT/128), 256, 0, stream>>>(x1, DIM, wscr, nullptr, kvb, DIM, DIM);

  // 8. chunked scan: local -> combine(fstate) -> correct(+gate fused)
  scan_local_kernel<<<BH * NC, 128, 0, stream>>>(wdec, proj, kvb, proj, Sbuf, Pbuf);
  scan_combine_kernel<<<BH, 256, 0, stream>>>(Sbuf, Pbuf, fstate);
  scan_correct_kernel<<<BH * NC, 128, 0, stream>>>(wdec, proj, rb, gb, Sbuf, proj);

  // 9. y2 = out_inner @ W_out^T -> wdec (reuse); A = proj y-region (lda=NPROJ)
  cvt_kernel<<<2048, 256, 0, stream>>>(W_o, wscr, nDD4);
  gemm_mfma<0,false><<<dim3(DIM/128, MTOT/128), 256, 0, stream>>>(proj, NPROJ, wscr, nullptr, wdec, DIM, DIM);

  // 10. out = LN(x1 + y2) -> fp32
  ln2_kernel<<<MTOT, 256, 0, stream>>>(x1, wdec, ln2g, ln2b, out);
}